// Round 2
// baseline (516.286 us; speedup 1.0000x reference)
//
#include <hip/hip_runtime.h>

#define NN 50000
#define NE 800000
#define SCAN_NB ((NN + 255) / 256)

typedef short bf16x8 __attribute__((ext_vector_type(8)));
typedef float f32x4 __attribute__((ext_vector_type(4)));
typedef unsigned u32x4 __attribute__((ext_vector_type(4)));

// ------------------------------------------------ bf16 helpers (ushort = bf16)
__device__ inline void bf16x8_to_f32(const u32x4 v, float* f) {
    f[0] = __uint_as_float(v.x << 16);
    f[1] = __uint_as_float(v.x & 0xffff0000u);
    f[2] = __uint_as_float(v.y << 16);
    f[3] = __uint_as_float(v.y & 0xffff0000u);
    f[4] = __uint_as_float(v.z << 16);
    f[5] = __uint_as_float(v.z & 0xffff0000u);
    f[6] = __uint_as_float(v.w << 16);
    f[7] = __uint_as_float(v.w & 0xffff0000u);
}

__device__ inline unsigned f32_to_bf16(float x) {  // RTNE
    unsigned u = __float_as_uint(x);
    return (u + 0x7fffu + ((u >> 16) & 1u)) >> 16;
}

__device__ inline u32x4 f32x8_to_bf16(const float* f) {
    u32x4 v;
    v.x = f32_to_bf16(f[0]) | (f32_to_bf16(f[1]) << 16);
    v.y = f32_to_bf16(f[2]) | (f32_to_bf16(f[3]) << 16);
    v.z = f32_to_bf16(f[4]) | (f32_to_bf16(f[5]) << 16);
    v.w = f32_to_bf16(f[6]) | (f32_to_bf16(f[7]) << 16);
    return v;
}

// ------------------------------------------------ hist + per-edge rank (8 edges/thread for atomic MLP)
__global__ __launch_bounds__(256) void hist_rank_kernel(const int* __restrict__ dst,
                                                        int* __restrict__ cnt,
                                                        int* __restrict__ rank) {
    int i = (blockIdx.x * 256 + threadIdx.x) * 8;
    if (i < NE) {  // NE % 8 == 0, so all 8 are in-bounds
        int4 d0 = *(const int4*)(dst + i);
        int4 d1 = *(const int4*)(dst + i + 4);
        int4 r0, r1;
        r0.x = atomicAdd(&cnt[d0.x], 1);
        r0.y = atomicAdd(&cnt[d0.y], 1);
        r0.z = atomicAdd(&cnt[d0.z], 1);
        r0.w = atomicAdd(&cnt[d0.w], 1);
        r1.x = atomicAdd(&cnt[d1.x], 1);
        r1.y = atomicAdd(&cnt[d1.y], 1);
        r1.z = atomicAdd(&cnt[d1.z], 1);
        r1.w = atomicAdd(&cnt[d1.w], 1);
        *(int4*)(rank + i) = r0;
        *(int4*)(rank + i + 4) = r1;
    }
}

// ------------------------------------------------ degree histogram (128 bins, LDS-privatized)
__global__ __launch_bounds__(256) void dhist_kernel(const int* __restrict__ cnt,
                                                    int* __restrict__ dh) {
    __shared__ int lh[128];
    int t = threadIdx.x;
    if (t < 128) lh[t] = 0;
    __syncthreads();
    int n = blockIdx.x * 256 + t;
    if (n < NN) {
        int d = cnt[n];
        if (d > 127) d = 127;
        atomicAdd(&lh[d], 1);
    }
    __syncthreads();
    if (t < 128 && lh[t] > 0) atomicAdd(&dh[t], lh[t]);
}

// ------------------------------------------------ descending-degree exclusive base
__global__ void dscan_kernel(const int* __restrict__ dh, int* __restrict__ dbase) {
    __shared__ int s[128];
    int t = threadIdx.x;
    s[t] = dh[t];
    __syncthreads();
    int sum = 0;
    for (int d = t + 1; d < 128; ++d) sum += s[d];
    dbase[t] = sum;  // nodes with higher degree come first
}

// ------------------------------------------------ assign new ids (counting sort by degree)
__global__ __launch_bounds__(256) void assign_kernel(const int* __restrict__ cnt,
                                                     const int* __restrict__ dbase,
                                                     int* __restrict__ dcur,
                                                     int* __restrict__ newid,
                                                     int* __restrict__ iperm,
                                                     int* __restrict__ len2) {
    __shared__ int lh[128];
    __shared__ int lbase[128];
    int t = threadIdx.x;
    if (t < 128) lh[t] = 0;
    __syncthreads();
    int n = blockIdx.x * 256 + t;
    int deg = 0, b = 0, lr = 0;
    bool act = (n < NN);
    if (act) {
        deg = cnt[n];
        b = (deg > 127) ? 127 : deg;
        lr = atomicAdd(&lh[b], 1);
    }
    __syncthreads();
    if (t < 128 && lh[t] > 0) lbase[t] = atomicAdd(&dcur[t], lh[t]);
    __syncthreads();
    if (act) {
        int id = dbase[b] + lbase[b] + lr;
        newid[n] = id;
        iperm[id] = n;
        len2[id] = deg;
    }
}

// ------------------------------------------------ 3-kernel parallel scan
__global__ __launch_bounds__(256) void scan_block_kernel(const int* __restrict__ cnt,
                                                         int* __restrict__ row_ptr,
                                                         int* __restrict__ partial,
                                                         int n) {
    __shared__ int wsums[4];
    int i = blockIdx.x * 256 + threadIdx.x;
    int v = (i < n) ? cnt[i] : 0;
    const int lane = threadIdx.x & 63;
    const int wid = threadIdx.x >> 6;
    int incl = v;
    #pragma unroll
    for (int off = 1; off < 64; off <<= 1) {
        int t = __shfl_up(incl, off);
        if (lane >= off) incl += t;
    }
    if (lane == 63) wsums[wid] = incl;
    __syncthreads();
    int woff = 0;
    #pragma unroll
    for (int w = 0; w < 4; ++w)
        if (w < wid) woff += wsums[w];
    if (i < n) row_ptr[i] = woff + incl - v;
    if (threadIdx.x == 0)
        partial[blockIdx.x] = wsums[0] + wsums[1] + wsums[2] + wsums[3];
}

__global__ __launch_bounds__(256) void scan_partials_kernel(int* __restrict__ partial,
                                                            int* __restrict__ pexcl,
                                                            int* __restrict__ row_ptr,
                                                            int np) {
    __shared__ int wsums[4];
    int v = (threadIdx.x < np) ? partial[threadIdx.x] : 0;
    const int lane = threadIdx.x & 63;
    const int wid = threadIdx.x >> 6;
    int incl = v;
    #pragma unroll
    for (int off = 1; off < 64; off <<= 1) {
        int t = __shfl_up(incl, off);
        if (lane >= off) incl += t;
    }
    if (lane == 63) wsums[wid] = incl;
    __syncthreads();
    int woff = 0;
    #pragma unroll
    for (int w = 0; w < 4; ++w)
        if (w < wid) woff += wsums[w];
    if (threadIdx.x < np) pexcl[threadIdx.x] = woff + incl - v;
    if (threadIdx.x == 0) row_ptr[NN] = NE;
}

__global__ __launch_bounds__(256) void scan_add_kernel(int* __restrict__ row_ptr,
                                                       const int* __restrict__ pexcl,
                                                       int n) {
    int i = blockIdx.x * 256 + threadIdx.x;
    if (i < n) row_ptr[i] += pexcl[blockIdx.x];
}

// ------------------------------------------------ rpn[n] = row_ptr2[newid[n]]
__global__ __launch_bounds__(256) void rpn_kernel(const int* __restrict__ row_ptr2,
                                                  const int* __restrict__ newid,
                                                  int* __restrict__ rpn) {
    int n = blockIdx.x * 256 + threadIdx.x;
    if (n < NN) rpn[n] = row_ptr2[newid[n]];
}

// ------------------------------------------------ CSR fill (atomic-free, 4B rec, permuted ids)
__global__ __launch_bounds__(256) void fill_kernel(const int* __restrict__ src,
                                                   const int* __restrict__ dst,
                                                   const float* __restrict__ w,
                                                   const int* __restrict__ rpn,
                                                   const int* __restrict__ rank,
                                                   const int* __restrict__ newid,
                                                   unsigned* __restrict__ er) {
    int i = blockIdx.x * blockDim.x + threadIdx.x;
    if (i < NE) {
        int p = rpn[dst[i]] + rank[i];
        er[p] = (f32_to_bf16(w[i]) << 16) | (unsigned)newid[src[i]];
    }
}

// ------------------------------------------------ weighted in-degree per node (new space)
__global__ __launch_bounds__(256) void degw_kernel(const int* __restrict__ row_ptr,
                                                   const unsigned* __restrict__ er,
                                                   float* __restrict__ degw) {
    int n = blockIdx.x * 256 + threadIdx.x;
    if (n < NN) {
        float s = 0.f;
        int end = row_ptr[n + 1];
        for (int e = row_ptr[n]; e < end; ++e)
            s += __uint_as_float(__builtin_nontemporal_load(er + e) & 0xffff0000u);
        degw[n] = s;
    }
}

// ------------------------------------------------ W12T[n][k] = sum_j W1[k][j]*W2[j][n]
__global__ __launch_bounds__(256) void w12t_kernel(const float* __restrict__ W1,
                                                   const float* __restrict__ W2,
                                                   unsigned short* __restrict__ W12T) {
    int i = blockIdx.x * 256 + threadIdx.x;  // i = n*256 + k, n<64, k<256
    if (i < 64 * 256) {
        int n = i >> 8, k = i & 255;
        float s = 0.f;
        for (int j = 0; j < 128; ++j)
            s += W1[(size_t)k * 128 + j] * W2[(size_t)j * 64 + n];
        W12T[i] = (unsigned short)f32_to_bf16(s);
    }
}

// ------------------------------------------------ c[d] = sum_k b1[k]*W2[k][d]
__global__ __launch_bounds__(64) void cvec_kernel(const float* __restrict__ b1,
                                                  const float* __restrict__ W2,
                                                  float* __restrict__ c) {
    int d = threadIdx.x;
    float s = 0.f;
    for (int k = 0; k < 128; ++k) s += b1[k] * W2[(size_t)k * 64 + d];
    c[d] = s;
}

// ------------------------------------------------ MFMA bf16 GEMM (A fp32), stores to permuted rows
template <int N, int K>
__global__ __launch_bounds__(256) void gemm_mfma_kernel(
    const float* __restrict__ A, const unsigned short* __restrict__ BT,
    const int* __restrict__ newid, unsigned short* __restrict__ C, int M) {
    constexpr int NT = N / 16;
    constexpr int KS = K / 32;
    __shared__ unsigned short As[64][40];
    __shared__ unsigned short Bs[N][40];

    const int tid = threadIdx.x;
    const int wave = tid >> 6;
    const int lane = tid & 63;
    const int lm = lane & 15;
    const int lq = lane >> 4;
    const int row0 = blockIdx.x * 64;
    const int m0 = wave * 16;

    f32x4 acc[NT] = {};

    for (int ks = 0; ks < KS; ++ks) {
        const int k0 = ks * 32;
        {
            int m = tid >> 2, kc = (tid & 3) * 8;
            int gm = row0 + m;
            if (gm >= M) gm = M - 1;
            float4 v0 = *(const float4*)(A + (size_t)gm * K + k0 + kc);
            float4 v1 = *(const float4*)(A + (size_t)gm * K + k0 + kc + 4);
            float f[8] = {v0.x, v0.y, v0.z, v0.w, v1.x, v1.y, v1.z, v1.w};
            *(u32x4*)&As[m][kc] = f32x8_to_bf16(f);
        }
        #pragma unroll
        for (int c = tid; c < N * 4; c += 256) {
            int n = c >> 2, kc = (c & 3) * 8;
            *(uint4*)&Bs[n][kc] = *(const uint4*)(BT + (size_t)n * K + k0 + kc);
        }
        __syncthreads();
        bf16x8 a = *(const bf16x8*)&As[m0 + lm][lq * 8];
        #pragma unroll
        for (int t = 0; t < NT; ++t) {
            bf16x8 b = *(const bf16x8*)&Bs[t * 16 + lm][lq * 8];
            acc[t] = __builtin_amdgcn_mfma_f32_16x16x32_bf16(a, b, acc[t], 0, 0, 0);
        }
        __syncthreads();
    }
    #pragma unroll
    for (int r = 0; r < 4; ++r) {
        int gm = row0 + m0 + lq * 4 + r;
        if (gm < M) {
            int pg = newid[gm];
            #pragma unroll
            for (int t = 0; t < NT; ++t)
                C[(size_t)pg * N + t * 16 + lm] =
                    (unsigned short)f32_to_bf16(acc[t][r]);
        }
    }
}

// ------------------------------------------------ propagation D=64 (bf16, 4B rec)
// XCD-partitioned half-split: blocks with (blockIdx%8)<4 handle dims [0,32),
// the rest handle [32,64). Each XCD's random-gather working set is then one
// 3.2 MB half of x, which fits its private 4 MB L2. er/h are streamed with
// nontemporal loads so they don't evict the hot x half.
// rec = bf16(w)<<16 | src (src < 65536 since NN=50000).
// MODE 0: out = acc                         (plain, conv1-fused)
// MODE 2: out = acc + degw[n]*c[d] + b2[d]  (conv2 epilogue)
// MODE 1: out = 0.9*acc + 0.1*h[n][d]       (APPNP step)
// remap: if non-null, store row index = remap[n] (final unpermute)
template <int MODE, bool OUT_BF16>
__global__ __launch_bounds__(256, 6) void prop_kernel(
    const int* __restrict__ row_ptr, const unsigned* __restrict__ er,
    const unsigned short* __restrict__ x, const float* __restrict__ cvec,
    const float* __restrict__ b2, const float* __restrict__ degw,
    const unsigned short* __restrict__ hbf, const int* __restrict__ remap,
    void* __restrict__ outv) {
    constexpr int D = 64;
    const int g = blockIdx.x & 7;
    const int half = g >> 2;                       // XCDs 0-3: half 0, 4-7: half 1
    const int nb = (blockIdx.x >> 3) * 4 + (g & 3);
    const int local = threadIdx.x >> 2;            // 64 nodes/block
    const int lane = threadIdx.x & 3;              // 4 threads/node, 16B each
    const int n = nb * 64 + local;
    if (n >= NN) return;
    const int dof = (half << 5) + lane * 8;        // dim offset within row

    int e = row_ptr[n];
    const int end = row_ptr[n + 1];

    float acc[8] = {};
    float f[8];
    for (; e + 3 < end; e += 4) {
        unsigned r0 = __builtin_nontemporal_load(er + e);
        unsigned r1 = __builtin_nontemporal_load(er + e + 1);
        unsigned r2 = __builtin_nontemporal_load(er + e + 2);
        unsigned r3 = __builtin_nontemporal_load(er + e + 3);
        u32x4 u0 = *(const u32x4*)(x + (size_t)(r0 & 0xffffu) * D + dof);
        u32x4 u1 = *(const u32x4*)(x + (size_t)(r1 & 0xffffu) * D + dof);
        u32x4 u2 = *(const u32x4*)(x + (size_t)(r2 & 0xffffu) * D + dof);
        u32x4 u3 = *(const u32x4*)(x + (size_t)(r3 & 0xffffu) * D + dof);
        float w0 = __uint_as_float(r0 & 0xffff0000u);
        float w1 = __uint_as_float(r1 & 0xffff0000u);
        float w2 = __uint_as_float(r2 & 0xffff0000u);
        float w3 = __uint_as_float(r3 & 0xffff0000u);
        bf16x8_to_f32(u0, f);
        #pragma unroll
        for (int j = 0; j < 8; ++j) acc[j] += w0 * f[j];
        bf16x8_to_f32(u1, f);
        #pragma unroll
        for (int j = 0; j < 8; ++j) acc[j] += w1 * f[j];
        bf16x8_to_f32(u2, f);
        #pragma unroll
        for (int j = 0; j < 8; ++j) acc[j] += w2 * f[j];
        bf16x8_to_f32(u3, f);
        #pragma unroll
        for (int j = 0; j < 8; ++j) acc[j] += w3 * f[j];
    }
    for (; e < end; ++e) {
        unsigned r0 = __builtin_nontemporal_load(er + e);
        u32x4 u0 = *(const u32x4*)(x + (size_t)(r0 & 0xffffu) * D + dof);
        float w0 = __uint_as_float(r0 & 0xffff0000u);
        bf16x8_to_f32(u0, f);
        #pragma unroll
        for (int j = 0; j < 8; ++j) acc[j] += w0 * f[j];
    }

    float r[8];
    if (MODE == 0) {
        #pragma unroll
        for (int j = 0; j < 8; ++j) r[j] = acc[j];
    } else if (MODE == 2) {
        float dw = degw[n];
        #pragma unroll
        for (int j = 0; j < 8; ++j)
            r[j] = acc[j] + dw * cvec[dof + j] + b2[dof + j];
    } else {
        u32x4 uh = __builtin_nontemporal_load(
            (const u32x4*)(hbf + (size_t)n * D + dof));
        float fh[8];
        bf16x8_to_f32(uh, fh);
        #pragma unroll
        for (int j = 0; j < 8; ++j) r[j] = 0.9f * acc[j] + 0.1f * fh[j];
    }

    const int ns = remap ? remap[n] : n;
    if (OUT_BF16) {
        *(u32x4*)((unsigned short*)outv + (size_t)ns * D + dof) = f32x8_to_bf16(r);
    } else {
        float* o = (float*)outv + (size_t)ns * D + dof;
        *(float4*)(o + 0) = make_float4(r[0], r[1], r[2], r[3]);
        *(float4*)(o + 4) = make_float4(r[4], r[5], r[6], r[7]);
    }
}

__global__ void write_scalar_kernel(float* p, float v) { *p = v; }

// ------------------------------------------------ launch
extern "C" void kernel_launch(void* const* d_in, const int* in_sizes, int n_in,
                              void* d_out, int out_size, void* d_ws, size_t ws_size,
                              hipStream_t stream) {
    const float* features = (const float*)d_in[0];
    const int* edge_index = (const int*)d_in[1];
    const float* edge_w = (const float*)d_in[2];
    const float* W1 = (const float*)d_in[3];
    const float* b1 = (const float*)d_in[4];
    const float* W2 = (const float*)d_in[5];
    const float* b2 = (const float*)d_in[6];
    const int* src = edge_index;        // edge_index[0]
    const int* dst = edge_index + NE;   // edge_index[1]

    char* ws = (char*)d_ws;
    auto carve = [&](size_t bytes) {
        char* p = ws;
        ws += (bytes + 255) & ~(size_t)255;
        return p;
    };
    int* cnt = (int*)carve((size_t)NN * 4);
    int* rank = (int*)carve((size_t)NE * 4);
    int* row_ptr2 = (int*)carve((size_t)(NN + 1) * 4);
    int* partial = (int*)carve((size_t)SCAN_NB * 4);
    int* pexcl = (int*)carve((size_t)SCAN_NB * 4);
    unsigned* erec = (unsigned*)carve((size_t)NE * 4);
    float* degw = (float*)carve((size_t)NN * 4);
    float* cvec = (float*)carve((size_t)64 * 4);
    unsigned short* W12T = (unsigned short*)carve((size_t)64 * 256 * 2);
    unsigned short* z_bf = (unsigned short*)carve((size_t)NN * 64 * 2);
    unsigned short* p1_bf = (unsigned short*)carve((size_t)NN * 64 * 2);
    unsigned short* h_bf = (unsigned short*)carve((size_t)NN * 64 * 2);
    unsigned short* xb0 = (unsigned short*)carve((size_t)NN * 64 * 2);
    unsigned short* xb1 = (unsigned short*)carve((size_t)NN * 64 * 2);
    int* newid = (int*)carve((size_t)NN * 4);
    int* iperm = (int*)carve((size_t)NN * 4);
    int* len2 = (int*)carve((size_t)NN * 4);
    int* rpn = (int*)carve((size_t)NN * 4);
    int* dh = (int*)carve((size_t)256 * 4);   // dh[128] + dcur[128]
    int* dcur = dh + 128;
    int* dbase = (int*)carve((size_t)128 * 4);

    const int EB = (NE + 255) / 256;
    const int EB8 = (NE / 8 + 255) / 256;
    const int NB = (NN + 255) / 256;
    const int HB = (NN + 63) / 64;                  // node-blocks per half
    const int PB = ((2 * HB + 7) / 8) * 8;          // prop grid (XCD-partitioned)

    // ---- CSR build (by destination) with degree-descending node relabeling ----
    hipMemsetAsync(cnt, 0, (size_t)NN * 4, stream);
    hipMemsetAsync(dh, 0, (size_t)256 * 4, stream);
    hist_rank_kernel<<<EB8, 256, 0, stream>>>(dst, cnt, rank);
    dhist_kernel<<<NB, 256, 0, stream>>>(cnt, dh);
    dscan_kernel<<<1, 128, 0, stream>>>(dh, dbase);
    assign_kernel<<<NB, 256, 0, stream>>>(cnt, dbase, dcur, newid, iperm, len2);
    scan_block_kernel<<<SCAN_NB, 256, 0, stream>>>(len2, row_ptr2, partial, NN);
    scan_partials_kernel<<<1, 256, 0, stream>>>(partial, pexcl, row_ptr2, SCAN_NB);
    scan_add_kernel<<<SCAN_NB, 256, 0, stream>>>(row_ptr2, pexcl, NN);
    rpn_kernel<<<NB, 256, 0, stream>>>(row_ptr2, newid, rpn);
    fill_kernel<<<EB, 256, 0, stream>>>(src, dst, edge_w, rpn, rank, newid, erec);
    degw_kernel<<<NB, 256, 0, stream>>>(row_ptr2, erec, degw);

    // ---- fused weights: W12T = (W1@W2)^T bf16, cvec = b1@W2 ----
    w12t_kernel<<<64, 256, 0, stream>>>(W1, W2, W12T);
    cvec_kernel<<<1, 64, 0, stream>>>(b1, W2, cvec);

    // ---- z = F @ W12  [NN,64] bf16, rows stored at newid[] ----
    gemm_mfma_kernel<64, 256>
        <<<(NN + 63) / 64, 256, 0, stream>>>(features, W12T, newid, z_bf, NN);

    // ---- p1 = prop(z);  h = prop(p1) + degw*c + b2 ----
    prop_kernel<0, true><<<PB, 256, 0, stream>>>(row_ptr2, erec, z_bf, nullptr,
                                                 nullptr, nullptr, nullptr,
                                                 nullptr, p1_bf);
    prop_kernel<2, true><<<PB, 256, 0, stream>>>(row_ptr2, erec, p1_bf, cvec, b2,
                                                 degw, nullptr, nullptr, h_bf);

    // ---- APPNP: 10 steps of x = 0.9*prop(x) + 0.1*h ----
    const unsigned short* x_cur = h_bf;
    for (int k = 0; k < 9; ++k) {
        unsigned short* out = (k & 1) ? xb1 : xb0;
        prop_kernel<1, true><<<PB, 256, 0, stream>>>(row_ptr2, erec, x_cur, nullptr,
                                                     nullptr, nullptr, h_bf,
                                                     nullptr, out);
        x_cur = out;
    }
    prop_kernel<1, false><<<PB, 256, 0, stream>>>(row_ptr2, erec, x_cur, nullptr,
                                                  nullptr, nullptr, h_bf, iperm,
                                                  (float*)d_out);

    // ---- second tuple element: the Python int 10 ----
    if (out_size > NN * 64) {
        write_scalar_kernel<<<1, 1, 0, stream>>>((float*)d_out + (size_t)NN * 64,
                                                 10.0f);
    }
}

// Round 3
// 395.220 us; speedup vs baseline: 1.3063x; 1.3063x over previous
//
#include <hip/hip_runtime.h>

#define NN 50000
#define NE 800000
#define SCAN_NB ((NN + 255) / 256)

typedef short bf16x8 __attribute__((ext_vector_type(8)));
typedef float f32x4 __attribute__((ext_vector_type(4)));
typedef unsigned u32x4 __attribute__((ext_vector_type(4)));

// ------------------------------------------------ bf16 helpers (ushort = bf16)
__device__ inline void bf16x8_to_f32(const u32x4 v, float* f) {
    f[0] = __uint_as_float(v.x << 16);
    f[1] = __uint_as_float(v.x & 0xffff0000u);
    f[2] = __uint_as_float(v.y << 16);
    f[3] = __uint_as_float(v.y & 0xffff0000u);
    f[4] = __uint_as_float(v.z << 16);
    f[5] = __uint_as_float(v.z & 0xffff0000u);
    f[6] = __uint_as_float(v.w << 16);
    f[7] = __uint_as_float(v.w & 0xffff0000u);
}

__device__ inline unsigned f32_to_bf16(float x) {  // RTNE
    unsigned u = __float_as_uint(x);
    return (u + 0x7fffu + ((u >> 16) & 1u)) >> 16;
}

__device__ inline u32x4 f32x8_to_bf16(const float* f) {
    u32x4 v;
    v.x = f32_to_bf16(f[0]) | (f32_to_bf16(f[1]) << 16);
    v.y = f32_to_bf16(f[2]) | (f32_to_bf16(f[3]) << 16);
    v.z = f32_to_bf16(f[4]) | (f32_to_bf16(f[5]) << 16);
    v.w = f32_to_bf16(f[6]) | (f32_to_bf16(f[7]) << 16);
    return v;
}

// ------------------------------------------------ hist + per-edge rank (8 edges/thread for atomic MLP)
__global__ __launch_bounds__(256) void hist_rank_kernel(const int* __restrict__ dst,
                                                        int* __restrict__ cnt,
                                                        int* __restrict__ rank) {
    int i = (blockIdx.x * 256 + threadIdx.x) * 8;
    if (i < NE) {  // NE % 8 == 0
        int4 d0 = *(const int4*)(dst + i);
        int4 d1 = *(const int4*)(dst + i + 4);
        int4 r0, r1;
        r0.x = atomicAdd(&cnt[d0.x], 1);
        r0.y = atomicAdd(&cnt[d0.y], 1);
        r0.z = atomicAdd(&cnt[d0.z], 1);
        r0.w = atomicAdd(&cnt[d0.w], 1);
        r1.x = atomicAdd(&cnt[d1.x], 1);
        r1.y = atomicAdd(&cnt[d1.y], 1);
        r1.z = atomicAdd(&cnt[d1.z], 1);
        r1.w = atomicAdd(&cnt[d1.w], 1);
        *(int4*)(rank + i) = r0;
        *(int4*)(rank + i + 4) = r1;
    }
}

// ------------------------------------------------ degree histogram (128 bins, LDS-privatized)
__global__ __launch_bounds__(256) void dhist_kernel(const int* __restrict__ cnt,
                                                    int* __restrict__ dh) {
    __shared__ int lh[128];
    int t = threadIdx.x;
    if (t < 128) lh[t] = 0;
    __syncthreads();
    int n = blockIdx.x * 256 + t;
    if (n < NN) {
        int d = cnt[n];
        if (d > 127) d = 127;
        atomicAdd(&lh[d], 1);
    }
    __syncthreads();
    if (t < 128 && lh[t] > 0) atomicAdd(&dh[t], lh[t]);
}

// ------------------------------------------------ descending-degree exclusive base
__global__ void dscan_kernel(const int* __restrict__ dh, int* __restrict__ dbase) {
    __shared__ int s[128];
    int t = threadIdx.x;
    s[t] = dh[t];
    __syncthreads();
    int sum = 0;
    for (int d = t + 1; d < 128; ++d) sum += s[d];
    dbase[t] = sum;  // nodes with higher degree come first
}

// ------------------------------------------------ assign new ids (counting sort by degree)
__global__ __launch_bounds__(256) void assign_kernel(const int* __restrict__ cnt,
                                                     const int* __restrict__ dbase,
                                                     int* __restrict__ dcur,
                                                     int* __restrict__ newid,
                                                     int* __restrict__ iperm,
                                                     int* __restrict__ len2) {
    __shared__ int lh[128];
    __shared__ int lbase[128];
    int t = threadIdx.x;
    if (t < 128) lh[t] = 0;
    __syncthreads();
    int n = blockIdx.x * 256 + t;
    int deg = 0, b = 0, lr = 0;
    bool act = (n < NN);
    if (act) {
        deg = cnt[n];
        b = (deg > 127) ? 127 : deg;
        lr = atomicAdd(&lh[b], 1);
    }
    __syncthreads();
    if (t < 128 && lh[t] > 0) lbase[t] = atomicAdd(&dcur[t], lh[t]);
    __syncthreads();
    if (act) {
        int id = dbase[b] + lbase[b] + lr;
        newid[n] = id;
        iperm[id] = n;
        len2[id] = deg;
    }
}

// ------------------------------------------------ 3-kernel parallel scan
__global__ __launch_bounds__(256) void scan_block_kernel(const int* __restrict__ cnt,
                                                         int* __restrict__ row_ptr,
                                                         int* __restrict__ partial,
                                                         int n) {
    __shared__ int wsums[4];
    int i = blockIdx.x * 256 + threadIdx.x;
    int v = (i < n) ? cnt[i] : 0;
    const int lane = threadIdx.x & 63;
    const int wid = threadIdx.x >> 6;
    int incl = v;
    #pragma unroll
    for (int off = 1; off < 64; off <<= 1) {
        int t = __shfl_up(incl, off);
        if (lane >= off) incl += t;
    }
    if (lane == 63) wsums[wid] = incl;
    __syncthreads();
    int woff = 0;
    #pragma unroll
    for (int w = 0; w < 4; ++w)
        if (w < wid) woff += wsums[w];
    if (i < n) row_ptr[i] = woff + incl - v;
    if (threadIdx.x == 0)
        partial[blockIdx.x] = wsums[0] + wsums[1] + wsums[2] + wsums[3];
}

__global__ __launch_bounds__(256) void scan_partials_kernel(int* __restrict__ partial,
                                                            int* __restrict__ pexcl,
                                                            int* __restrict__ row_ptr,
                                                            int np) {
    __shared__ int wsums[4];
    int v = (threadIdx.x < np) ? partial[threadIdx.x] : 0;
    const int lane = threadIdx.x & 63;
    const int wid = threadIdx.x >> 6;
    int incl = v;
    #pragma unroll
    for (int off = 1; off < 64; off <<= 1) {
        int t = __shfl_up(incl, off);
        if (lane >= off) incl += t;
    }
    if (lane == 63) wsums[wid] = incl;
    __syncthreads();
    int woff = 0;
    #pragma unroll
    for (int w = 0; w < 4; ++w)
        if (w < wid) woff += wsums[w];
    if (threadIdx.x < np) pexcl[threadIdx.x] = woff + incl - v;
    if (threadIdx.x == 0) row_ptr[NN] = NE;
}

__global__ __launch_bounds__(256) void scan_add_kernel(int* __restrict__ row_ptr,
                                                       const int* __restrict__ pexcl,
                                                       int n) {
    int i = blockIdx.x * 256 + threadIdx.x;
    if (i < n) row_ptr[i] += pexcl[blockIdx.x];
}

// ------------------------------------------------ rpn[n] = row_ptr2[newid[n]]
__global__ __launch_bounds__(256) void rpn_kernel(const int* __restrict__ row_ptr2,
                                                  const int* __restrict__ newid,
                                                  int* __restrict__ rpn) {
    int n = blockIdx.x * 256 + threadIdx.x;
    if (n < NN) rpn[n] = row_ptr2[newid[n]];
}

// ------------------------------------------------ CSR fill (atomic-free, 4B rec, permuted ids)
__global__ __launch_bounds__(256) void fill_kernel(const int* __restrict__ src,
                                                   const int* __restrict__ dst,
                                                   const float* __restrict__ w,
                                                   const int* __restrict__ rpn,
                                                   const int* __restrict__ rank,
                                                   const int* __restrict__ newid,
                                                   unsigned* __restrict__ er) {
    int i = blockIdx.x * blockDim.x + threadIdx.x;
    if (i < NE) {
        int p = rpn[dst[i]] + rank[i];
        er[p] = (f32_to_bf16(w[i]) << 16) | (unsigned)newid[src[i]];
    }
}

// ------------------------------------------------ weighted in-degree per node (new space)
__global__ __launch_bounds__(256) void degw_kernel(const int* __restrict__ row_ptr,
                                                   const unsigned* __restrict__ er,
                                                   float* __restrict__ degw) {
    int n = blockIdx.x * 256 + threadIdx.x;
    if (n < NN) {
        float s = 0.f;
        int end = row_ptr[n + 1];
        for (int e = row_ptr[n]; e < end; ++e)
            s += __uint_as_float(er[e] & 0xffff0000u);
        degw[n] = s;
    }
}

// ------------------------------------------------ W12T[n][k] = sum_j W1[k][j]*W2[j][n]
__global__ __launch_bounds__(256) void w12t_kernel(const float* __restrict__ W1,
                                                   const float* __restrict__ W2,
                                                   unsigned short* __restrict__ W12T) {
    int i = blockIdx.x * 256 + threadIdx.x;  // i = n*256 + k, n<64, k<256
    if (i < 64 * 256) {
        int n = i >> 8, k = i & 255;
        float s = 0.f;
        for (int j = 0; j < 128; ++j)
            s += W1[(size_t)k * 128 + j] * W2[(size_t)j * 64 + n];
        W12T[i] = (unsigned short)f32_to_bf16(s);
    }
}

// ------------------------------------------------ c[d] = sum_k b1[k]*W2[k][d]
__global__ __launch_bounds__(64) void cvec_kernel(const float* __restrict__ b1,
                                                  const float* __restrict__ W2,
                                                  float* __restrict__ c) {
    int d = threadIdx.x;
    float s = 0.f;
    for (int k = 0; k < 128; ++k) s += b1[k] * W2[(size_t)k * 64 + d];
    c[d] = s;
}

// ------------------------------------------------ MFMA bf16 GEMM (A fp32)
// Output stored SPLIT: C is [2][NN][32] bf16 — dims 0-31 in half 0, 32-63 in half 1.
// Rows are stored at permuted index newid[gm].
template <int N, int K>
__global__ __launch_bounds__(256) void gemm_mfma_kernel(
    const float* __restrict__ A, const unsigned short* __restrict__ BT,
    const int* __restrict__ newid, unsigned short* __restrict__ C, int M) {
    constexpr int NT = N / 16;
    constexpr int KS = K / 32;
    __shared__ unsigned short As[64][40];
    __shared__ unsigned short Bs[N][40];

    const int tid = threadIdx.x;
    const int wave = tid >> 6;
    const int lane = tid & 63;
    const int lm = lane & 15;
    const int lq = lane >> 4;
    const int row0 = blockIdx.x * 64;
    const int m0 = wave * 16;

    f32x4 acc[NT] = {};

    for (int ks = 0; ks < KS; ++ks) {
        const int k0 = ks * 32;
        {
            int m = tid >> 2, kc = (tid & 3) * 8;
            int gm = row0 + m;
            if (gm >= M) gm = M - 1;
            float4 v0 = *(const float4*)(A + (size_t)gm * K + k0 + kc);
            float4 v1 = *(const float4*)(A + (size_t)gm * K + k0 + kc + 4);
            float f[8] = {v0.x, v0.y, v0.z, v0.w, v1.x, v1.y, v1.z, v1.w};
            *(u32x4*)&As[m][kc] = f32x8_to_bf16(f);
        }
        #pragma unroll
        for (int c = tid; c < N * 4; c += 256) {
            int n = c >> 2, kc = (c & 3) * 8;
            *(uint4*)&Bs[n][kc] = *(const uint4*)(BT + (size_t)n * K + k0 + kc);
        }
        __syncthreads();
        bf16x8 a = *(const bf16x8*)&As[m0 + lm][lq * 8];
        #pragma unroll
        for (int t = 0; t < NT; ++t) {
            bf16x8 b = *(const bf16x8*)&Bs[t * 16 + lm][lq * 8];
            acc[t] = __builtin_amdgcn_mfma_f32_16x16x32_bf16(a, b, acc[t], 0, 0, 0);
        }
        __syncthreads();
    }
    #pragma unroll
    for (int r = 0; r < 4; ++r) {
        int gm = row0 + m0 + lq * 4 + r;
        if (gm < M) {
            int pg = newid[gm];
            #pragma unroll
            for (int t = 0; t < NT; ++t) {
                int d = t * 16 + lm;  // 0..63
                C[(size_t)(d >> 5) * NN * 32 + (size_t)pg * 32 + (d & 31)] =
                    (unsigned short)f32_to_bf16(acc[t][r]);
            }
        }
    }
}

// ------------------------------------------------ propagation, XCD-split compact halves
// All bf16 feature buffers are [2][NN][32]: half h = compact 3.2 MB array (64 B rows,
// every cacheline used). Blocks with (blockIdx%8)<4 run on XCDs 0-3 and gather only
// half 0; the rest gather only half 1 — each XCD's random-gather working set is one
// compact 3.2 MB array that fits its private 4 MB L2.
// rec = bf16(w)<<16 | src (src < 65536 since NN=50000).
// MODE 0: out = acc;  MODE 2: out = acc + degw[n]*c[d] + b2[d];  MODE 1: 0.9*acc+0.1*h
template <int MODE, bool OUT_BF16>
__global__ __launch_bounds__(256, 6) void prop_kernel(
    const int* __restrict__ row_ptr, const unsigned* __restrict__ er,
    const unsigned short* __restrict__ x, const float* __restrict__ cvec,
    const float* __restrict__ b2, const float* __restrict__ degw,
    const unsigned short* __restrict__ hbf, const int* __restrict__ remap,
    void* __restrict__ outv) {
    constexpr int HD = 32;
    const int g = blockIdx.x & 7;
    const int half = g >> 2;                       // XCDs 0-3: half 0, 4-7: half 1
    const int nb = (blockIdx.x >> 3) * 4 + (g & 3);
    const int local = threadIdx.x >> 2;            // 64 nodes/block
    const int lane = threadIdx.x & 3;              // 4 lanes/node, 16 B each
    const int n = nb * 64 + local;
    if (n >= NN) return;

    const unsigned short* __restrict__ xh = x + (size_t)half * NN * HD;
    const int off = lane * 8;

    int e = row_ptr[n];
    const int end = row_ptr[n + 1];

    float acc[8] = {};
    float f[8];
    for (; e + 3 < end; e += 4) {
        unsigned r0 = er[e], r1 = er[e + 1], r2 = er[e + 2], r3 = er[e + 3];
        u32x4 u0 = *(const u32x4*)(xh + (size_t)(r0 & 0xffffu) * HD + off);
        u32x4 u1 = *(const u32x4*)(xh + (size_t)(r1 & 0xffffu) * HD + off);
        u32x4 u2 = *(const u32x4*)(xh + (size_t)(r2 & 0xffffu) * HD + off);
        u32x4 u3 = *(const u32x4*)(xh + (size_t)(r3 & 0xffffu) * HD + off);
        float w0 = __uint_as_float(r0 & 0xffff0000u);
        float w1 = __uint_as_float(r1 & 0xffff0000u);
        float w2 = __uint_as_float(r2 & 0xffff0000u);
        float w3 = __uint_as_float(r3 & 0xffff0000u);
        bf16x8_to_f32(u0, f);
        #pragma unroll
        for (int j = 0; j < 8; ++j) acc[j] += w0 * f[j];
        bf16x8_to_f32(u1, f);
        #pragma unroll
        for (int j = 0; j < 8; ++j) acc[j] += w1 * f[j];
        bf16x8_to_f32(u2, f);
        #pragma unroll
        for (int j = 0; j < 8; ++j) acc[j] += w2 * f[j];
        bf16x8_to_f32(u3, f);
        #pragma unroll
        for (int j = 0; j < 8; ++j) acc[j] += w3 * f[j];
    }
    for (; e < end; ++e) {
        unsigned r0 = er[e];
        u32x4 u0 = *(const u32x4*)(xh + (size_t)(r0 & 0xffffu) * HD + off);
        float w0 = __uint_as_float(r0 & 0xffff0000u);
        bf16x8_to_f32(u0, f);
        #pragma unroll
        for (int j = 0; j < 8; ++j) acc[j] += w0 * f[j];
    }

    float r[8];
    if (MODE == 0) {
        #pragma unroll
        for (int j = 0; j < 8; ++j) r[j] = acc[j];
    } else if (MODE == 2) {
        float dw = degw[n];
        const int dof = half * 32 + off;
        #pragma unroll
        for (int j = 0; j < 8; ++j)
            r[j] = acc[j] + dw * cvec[dof + j] + b2[dof + j];
    } else {
        u32x4 uh = *(const u32x4*)(hbf + (size_t)half * NN * HD + (size_t)n * HD + off);
        float fh[8];
        bf16x8_to_f32(uh, fh);
        #pragma unroll
        for (int j = 0; j < 8; ++j) r[j] = 0.9f * acc[j] + 0.1f * fh[j];
    }

    if (OUT_BF16) {
        *(u32x4*)((unsigned short*)outv + (size_t)half * NN * HD + (size_t)n * HD +
                  off) = f32x8_to_bf16(r);
    } else {
        const int ns = remap ? remap[n] : n;
        float* o = (float*)outv + (size_t)ns * 64 + half * 32 + off;
        *(float4*)(o + 0) = make_float4(r[0], r[1], r[2], r[3]);
        *(float4*)(o + 4) = make_float4(r[4], r[5], r[6], r[7]);
    }
}

__global__ void write_scalar_kernel(float* p, float v) { *p = v; }

// ------------------------------------------------ launch
extern "C" void kernel_launch(void* const* d_in, const int* in_sizes, int n_in,
                              void* d_out, int out_size, void* d_ws, size_t ws_size,
                              hipStream_t stream) {
    const float* features = (const float*)d_in[0];
    const int* edge_index = (const int*)d_in[1];
    const float* edge_w = (const float*)d_in[2];
    const float* W1 = (const float*)d_in[3];
    const float* b1 = (const float*)d_in[4];
    const float* W2 = (const float*)d_in[5];
    const float* b2 = (const float*)d_in[6];
    const int* src = edge_index;        // edge_index[0]
    const int* dst = edge_index + NE;   // edge_index[1]

    char* ws = (char*)d_ws;
    auto carve = [&](size_t bytes) {
        char* p = ws;
        ws += (bytes + 255) & ~(size_t)255;
        return p;
    };
    int* cnt = (int*)carve((size_t)NN * 4);
    int* rank = (int*)carve((size_t)NE * 4);
    int* row_ptr2 = (int*)carve((size_t)(NN + 1) * 4);
    int* partial = (int*)carve((size_t)SCAN_NB * 4);
    int* pexcl = (int*)carve((size_t)SCAN_NB * 4);
    unsigned* erec = (unsigned*)carve((size_t)NE * 4);
    float* degw = (float*)carve((size_t)NN * 4);
    float* cvec = (float*)carve((size_t)64 * 4);
    unsigned short* W12T = (unsigned short*)carve((size_t)64 * 256 * 2);
    unsigned short* z_bf = (unsigned short*)carve((size_t)NN * 64 * 2);
    unsigned short* p1_bf = (unsigned short*)carve((size_t)NN * 64 * 2);
    unsigned short* h_bf = (unsigned short*)carve((size_t)NN * 64 * 2);
    unsigned short* xb0 = (unsigned short*)carve((size_t)NN * 64 * 2);
    unsigned short* xb1 = (unsigned short*)carve((size_t)NN * 64 * 2);
    int* newid = (int*)carve((size_t)NN * 4);
    int* iperm = (int*)carve((size_t)NN * 4);
    int* len2 = (int*)carve((size_t)NN * 4);
    int* rpn = (int*)carve((size_t)NN * 4);
    int* dh = (int*)carve((size_t)256 * 4);   // dh[128] + dcur[128]
    int* dcur = dh + 128;
    int* dbase = (int*)carve((size_t)128 * 4);

    const int EB = (NE + 255) / 256;
    const int EB8 = (NE / 8 + 255) / 256;
    const int NB = (NN + 255) / 256;
    const int HB = (NN + 63) / 64;                  // node-blocks per half
    const int PB = ((2 * HB + 7) / 8) * 8;          // prop grid (XCD-partitioned)

    // ---- CSR build (by destination) with degree-descending node relabeling ----
    hipMemsetAsync(cnt, 0, (size_t)NN * 4, stream);
    hipMemsetAsync(dh, 0, (size_t)256 * 4, stream);
    hist_rank_kernel<<<EB8, 256, 0, stream>>>(dst, cnt, rank);
    dhist_kernel<<<NB, 256, 0, stream>>>(cnt, dh);
    dscan_kernel<<<1, 128, 0, stream>>>(dh, dbase);
    assign_kernel<<<NB, 256, 0, stream>>>(cnt, dbase, dcur, newid, iperm, len2);
    scan_block_kernel<<<SCAN_NB, 256, 0, stream>>>(len2, row_ptr2, partial, NN);
    scan_partials_kernel<<<1, 256, 0, stream>>>(partial, pexcl, row_ptr2, SCAN_NB);
    scan_add_kernel<<<SCAN_NB, 256, 0, stream>>>(row_ptr2, pexcl, NN);
    rpn_kernel<<<NB, 256, 0, stream>>>(row_ptr2, newid, rpn);
    fill_kernel<<<EB, 256, 0, stream>>>(src, dst, edge_w, rpn, rank, newid, erec);
    degw_kernel<<<NB, 256, 0, stream>>>(row_ptr2, erec, degw);

    // ---- fused weights: W12T = (W1@W2)^T bf16, cvec = b1@W2 ----
    w12t_kernel<<<64, 256, 0, stream>>>(W1, W2, W12T);
    cvec_kernel<<<1, 64, 0, stream>>>(b1, W2, cvec);

    // ---- z = F @ W12  [2][NN][32] bf16 split halves, rows at newid[] ----
    gemm_mfma_kernel<64, 256>
        <<<(NN + 63) / 64, 256, 0, stream>>>(features, W12T, newid, z_bf, NN);

    // ---- p1 = prop(z);  h = prop(p1) + degw*c + b2 ----
    prop_kernel<0, true><<<PB, 256, 0, stream>>>(row_ptr2, erec, z_bf, nullptr,
                                                 nullptr, nullptr, nullptr,
                                                 nullptr, p1_bf);
    prop_kernel<2, true><<<PB, 256, 0, stream>>>(row_ptr2, erec, p1_bf, cvec, b2,
                                                 degw, nullptr, nullptr, h_bf);

    // ---- APPNP: 10 steps of x = 0.9*prop(x) + 0.1*h ----
    const unsigned short* x_cur = h_bf;
    for (int k = 0; k < 9; ++k) {
        unsigned short* out = (k & 1) ? xb1 : xb0;
        prop_kernel<1, true><<<PB, 256, 0, stream>>>(row_ptr2, erec, x_cur, nullptr,
                                                     nullptr, nullptr, h_bf,
                                                     nullptr, out);
        x_cur = out;
    }
    prop_kernel<1, false><<<PB, 256, 0, stream>>>(row_ptr2, erec, x_cur, nullptr,
                                                  nullptr, nullptr, h_bf, iperm,
                                                  (float*)d_out);

    // ---- second tuple element: the Python int 10 ----
    if (out_size > NN * 64) {
        write_scalar_kernel<<<1, 1, 0, stream>>>((float*)d_out + (size_t)NN * 64,
                                                 10.0f);
    }
}

// Round 4
// 381.268 us; speedup vs baseline: 1.3541x; 1.0366x over previous
//
#include <hip/hip_runtime.h>

#define NN 50000
#define NE 800000
#define SCAN_NB ((NN + 255) / 256)
#define GEMM_NB ((NN + 63) / 64)
#define CNT_NB ((NE / 8 + 255) / 256)

typedef short bf16x8 __attribute__((ext_vector_type(8)));
typedef float f32x4 __attribute__((ext_vector_type(4)));
typedef unsigned u32x4 __attribute__((ext_vector_type(4)));

// ------------------------------------------------ bf16 helpers (ushort = bf16)
__device__ inline void bf16x8_to_f32(const u32x4 v, float* f) {
    f[0] = __uint_as_float(v.x << 16);
    f[1] = __uint_as_float(v.x & 0xffff0000u);
    f[2] = __uint_as_float(v.y << 16);
    f[3] = __uint_as_float(v.y & 0xffff0000u);
    f[4] = __uint_as_float(v.z << 16);
    f[5] = __uint_as_float(v.z & 0xffff0000u);
    f[6] = __uint_as_float(v.w << 16);
    f[7] = __uint_as_float(v.w & 0xffff0000u);
}

__device__ inline unsigned f32_to_bf16(float x) {  // RTNE
    unsigned u = __float_as_uint(x);
    return (u + 0x7fffu + ((u >> 16) & 1u)) >> 16;
}

__device__ inline u32x4 f32x8_to_bf16(const float* f) {
    u32x4 v;
    v.x = f32_to_bf16(f[0]) | (f32_to_bf16(f[1]) << 16);
    v.y = f32_to_bf16(f[2]) | (f32_to_bf16(f[3]) << 16);
    v.z = f32_to_bf16(f[4]) | (f32_to_bf16(f[5]) << 16);
    v.w = f32_to_bf16(f[6]) | (f32_to_bf16(f[7]) << 16);
    return v;
}

// ================================================ K1: fused {edge-count, W12T, cvec}
// count: fire-and-forget atomics (no return value -> no vmcnt round-trip wait).
// w12t:  W12T[n][k] = sum_j W1[k][j]*W2[j][n]   (64x256 bf16)
// cvec:  c[d] = sum_k b1[k]*W2[k][d]
__global__ __launch_bounds__(256) void fused_pre_kernel(
    const int* __restrict__ dst, int* __restrict__ cnt,
    const float* __restrict__ W1, const float* __restrict__ W2,
    unsigned short* __restrict__ W12T, const float* __restrict__ b1,
    float* __restrict__ cvec) {
    const int b = blockIdx.x;
    if (b < CNT_NB) {
        int i = (b * 256 + threadIdx.x) * 8;
        if (i < NE) {  // NE % 8 == 0
            int4 d0 = *(const int4*)(dst + i);
            int4 d1 = *(const int4*)(dst + i + 4);
            atomicAdd(&cnt[d0.x], 1);
            atomicAdd(&cnt[d0.y], 1);
            atomicAdd(&cnt[d0.z], 1);
            atomicAdd(&cnt[d0.w], 1);
            atomicAdd(&cnt[d1.x], 1);
            atomicAdd(&cnt[d1.y], 1);
            atomicAdd(&cnt[d1.z], 1);
            atomicAdd(&cnt[d1.w], 1);
        }
    } else if (b < CNT_NB + 64) {
        int i = (b - CNT_NB) * 256 + threadIdx.x;  // i = n*256 + k, n<64, k<256
        int n = i >> 8, k = i & 255;
        float s = 0.f;
        for (int j = 0; j < 128; ++j)
            s += W1[(size_t)k * 128 + j] * W2[(size_t)j * 64 + n];
        W12T[i] = (unsigned short)f32_to_bf16(s);
    } else {
        int d = threadIdx.x;
        if (d < 64) {
            float s = 0.f;
            for (int k = 0; k < 128; ++k) s += b1[k] * W2[(size_t)k * 64 + d];
            cvec[d] = s;
        }
    }
}

// ================================================ K2: fused {scan_block, MFMA GEMM}
// scan blocks [0, SCAN_NB): per-256-chunk exclusive scan of cnt -> row_ptr, partial
// gemm blocks [SCAN_NB, ...): z[NN,64] bf16 = features[NN,256] @ W12 (BT form)
__global__ __launch_bounds__(256) void fused_scan_gemm_kernel(
    const int* __restrict__ cnt, int* __restrict__ row_ptr,
    int* __restrict__ partial, const float* __restrict__ A,
    const unsigned short* __restrict__ BT, unsigned short* __restrict__ C) {
    __shared__ int wsums[4];
    __shared__ unsigned short As[64][40];
    __shared__ unsigned short Bs[64][40];

    if (blockIdx.x < SCAN_NB) {
        int i = blockIdx.x * 256 + threadIdx.x;
        int v = (i < NN) ? cnt[i] : 0;
        const int lane = threadIdx.x & 63;
        const int wid = threadIdx.x >> 6;
        int incl = v;
        #pragma unroll
        for (int off = 1; off < 64; off <<= 1) {
            int t = __shfl_up(incl, off);
            if (lane >= off) incl += t;
        }
        if (lane == 63) wsums[wid] = incl;
        __syncthreads();
        int woff = 0;
        #pragma unroll
        for (int w = 0; w < 4; ++w)
            if (w < wid) woff += wsums[w];
        if (i < NN) row_ptr[i] = woff + incl - v;
        if (threadIdx.x == 0)
            partial[blockIdx.x] = wsums[0] + wsums[1] + wsums[2] + wsums[3];
        return;
    }

    constexpr int N = 64, K = 256;
    constexpr int NT = N / 16;
    constexpr int KS = K / 32;
    const int tid = threadIdx.x;
    const int wave = tid >> 6;
    const int lane = tid & 63;
    const int lm = lane & 15;
    const int lq = lane >> 4;
    const int row0 = (blockIdx.x - SCAN_NB) * 64;
    const int m0 = wave * 16;

    f32x4 acc[NT] = {};

    for (int ks = 0; ks < KS; ++ks) {
        const int k0 = ks * 32;
        {
            int m = tid >> 2, kc = (tid & 3) * 8;
            int gm = row0 + m;
            if (gm >= NN) gm = NN - 1;
            float4 v0 = *(const float4*)(A + (size_t)gm * K + k0 + kc);
            float4 v1 = *(const float4*)(A + (size_t)gm * K + k0 + kc + 4);
            float f[8] = {v0.x, v0.y, v0.z, v0.w, v1.x, v1.y, v1.z, v1.w};
            *(u32x4*)&As[m][kc] = f32x8_to_bf16(f);
        }
        #pragma unroll
        for (int c = tid; c < N * 4; c += 256) {
            int n = c >> 2, kc = (c & 3) * 8;
            *(uint4*)&Bs[n][kc] = *(const uint4*)(BT + (size_t)n * K + k0 + kc);
        }
        __syncthreads();
        bf16x8 a = *(const bf16x8*)&As[m0 + lm][lq * 8];
        #pragma unroll
        for (int t = 0; t < NT; ++t) {
            bf16x8 b = *(const bf16x8*)&Bs[t * 16 + lm][lq * 8];
            acc[t] = __builtin_amdgcn_mfma_f32_16x16x32_bf16(a, b, acc[t], 0, 0, 0);
        }
        __syncthreads();
    }
    #pragma unroll
    for (int r = 0; r < 4; ++r) {
        int gm = row0 + m0 + lq * 4 + r;
        if (gm < NN) {
            #pragma unroll
            for (int t = 0; t < NT; ++t)
                C[(size_t)gm * N + t * 16 + lm] =
                    (unsigned short)f32_to_bf16(acc[t][r]);
        }
    }
}

// ------------------------------------------------ scan of per-block partials
__global__ __launch_bounds__(256) void scan_partials_kernel(int* __restrict__ partial,
                                                            int* __restrict__ pexcl,
                                                            int* __restrict__ row_ptr,
                                                            int np) {
    __shared__ int wsums[4];
    int v = (threadIdx.x < np) ? partial[threadIdx.x] : 0;
    const int lane = threadIdx.x & 63;
    const int wid = threadIdx.x >> 6;
    int incl = v;
    #pragma unroll
    for (int off = 1; off < 64; off <<= 1) {
        int t = __shfl_up(incl, off);
        if (lane >= off) incl += t;
    }
    if (lane == 63) wsums[wid] = incl;
    __syncthreads();
    int woff = 0;
    #pragma unroll
    for (int w = 0; w < 4; ++w)
        if (w < wid) woff += wsums[w];
    if (threadIdx.x < np) pexcl[threadIdx.x] = woff + incl - v;
    if (threadIdx.x == 0) row_ptr[NN] = NE;
}

// ------------------------------------------------ scan_add + cursor copy
__global__ __launch_bounds__(256) void scan_add_cursor_kernel(
    int* __restrict__ row_ptr, const int* __restrict__ pexcl,
    int* __restrict__ cursor, int n) {
    int i = blockIdx.x * 256 + threadIdx.x;
    if (i < n) {
        int v = row_ptr[i] + pexcl[blockIdx.x];
        row_ptr[i] = v;
        cursor[i] = v;
    }
}

// ------------------------------------------------ CSR fill via cursor atomics
// Order within a node's bucket is race-determined; fp32 reorder noise << bf16 noise.
__global__ __launch_bounds__(256) void fill_kernel(const int* __restrict__ src,
                                                   const int* __restrict__ dst,
                                                   const float* __restrict__ w,
                                                   int* __restrict__ cursor,
                                                   unsigned* __restrict__ er) {
    int i = (blockIdx.x * 256 + threadIdx.x) * 4;
    if (i < NE) {  // NE % 4 == 0
        int4 d = *(const int4*)(dst + i);
        int4 s = *(const int4*)(src + i);
        float4 wv = *(const float4*)(w + i);
        int p0 = atomicAdd(&cursor[d.x], 1);
        int p1 = atomicAdd(&cursor[d.y], 1);
        int p2 = atomicAdd(&cursor[d.z], 1);
        int p3 = atomicAdd(&cursor[d.w], 1);
        er[p0] = (f32_to_bf16(wv.x) << 16) | (unsigned)s.x;
        er[p1] = (f32_to_bf16(wv.y) << 16) | (unsigned)s.y;
        er[p2] = (f32_to_bf16(wv.z) << 16) | (unsigned)s.z;
        er[p3] = (f32_to_bf16(wv.w) << 16) | (unsigned)s.w;
    }
}

// ------------------------------------------------ propagation D=64 (bf16, 4B rec)
// rec = bf16(w)<<16 | src (src < 65536 since NN=50000).
// MODE 0: out = acc                         (plain, conv1-fused; DEGW: also sum w)
// MODE 2: out = acc + degw[n]*c[d] + b2[d]  (conv2 epilogue)
// MODE 1: out = 0.9*acc + 0.1*h[n][d]       (APPNP step)
template <int MODE, bool OUT_BF16, bool DEGW>
__global__ __launch_bounds__(256, 4) void prop_kernel(
    const int* __restrict__ row_ptr, const unsigned* __restrict__ er,
    const unsigned short* __restrict__ x, const float* __restrict__ cvec,
    const float* __restrict__ b2, float* __restrict__ degw,
    const unsigned short* __restrict__ hbf, void* __restrict__ outv) {
    constexpr int D = 64;
    const int local = threadIdx.x >> 3;     // node within block (32/block)
    const int lane = threadIdx.x & 7;       // 8 threads/node, 16B each
    const int n = blockIdx.x * 32 + local;
    if (n >= NN) return;

    int e = row_ptr[n];
    const int end = row_ptr[n + 1];

    float acc[8] = {};
    float sw = 0.f;
    float f[8];
    for (; e + 3 < end; e += 4) {
        unsigned r0 = er[e], r1 = er[e + 1], r2 = er[e + 2], r3 = er[e + 3];
        u32x4 u0 = *(const u32x4*)(x + (size_t)(r0 & 0xffffu) * D + lane * 8);
        u32x4 u1 = *(const u32x4*)(x + (size_t)(r1 & 0xffffu) * D + lane * 8);
        u32x4 u2 = *(const u32x4*)(x + (size_t)(r2 & 0xffffu) * D + lane * 8);
        u32x4 u3 = *(const u32x4*)(x + (size_t)(r3 & 0xffffu) * D + lane * 8);
        float w0 = __uint_as_float(r0 & 0xffff0000u);
        float w1 = __uint_as_float(r1 & 0xffff0000u);
        float w2 = __uint_as_float(r2 & 0xffff0000u);
        float w3 = __uint_as_float(r3 & 0xffff0000u);
        if (DEGW) sw += (w0 + w1) + (w2 + w3);
        bf16x8_to_f32(u0, f);
        #pragma unroll
        for (int j = 0; j < 8; ++j) acc[j] += w0 * f[j];
        bf16x8_to_f32(u1, f);
        #pragma unroll
        for (int j = 0; j < 8; ++j) acc[j] += w1 * f[j];
        bf16x8_to_f32(u2, f);
        #pragma unroll
        for (int j = 0; j < 8; ++j) acc[j] += w2 * f[j];
        bf16x8_to_f32(u3, f);
        #pragma unroll
        for (int j = 0; j < 8; ++j) acc[j] += w3 * f[j];
    }
    for (; e < end; ++e) {
        unsigned r0 = er[e];
        u32x4 u0 = *(const u32x4*)(x + (size_t)(r0 & 0xffffu) * D + lane * 8);
        float w0 = __uint_as_float(r0 & 0xffff0000u);
        if (DEGW) sw += w0;
        bf16x8_to_f32(u0, f);
        #pragma unroll
        for (int j = 0; j < 8; ++j) acc[j] += w0 * f[j];
    }

    if (DEGW) {
        if (lane == 0) degw[n] = sw;
    }

    float r[8];
    if (MODE == 0) {
        #pragma unroll
        for (int j = 0; j < 8; ++j) r[j] = acc[j];
    } else if (MODE == 2) {
        float dw = degw[n];
        #pragma unroll
        for (int j = 0; j < 8; ++j)
            r[j] = acc[j] + dw * cvec[lane * 8 + j] + b2[lane * 8 + j];
    } else {
        u32x4 uh = *(const u32x4*)(hbf + (size_t)n * D + lane * 8);
        float fh[8];
        bf16x8_to_f32(uh, fh);
        #pragma unroll
        for (int j = 0; j < 8; ++j) r[j] = 0.9f * acc[j] + 0.1f * fh[j];
    }

    if (OUT_BF16) {
        *(u32x4*)((unsigned short*)outv + (size_t)n * D + lane * 8) =
            f32x8_to_bf16(r);
    } else {
        float* o = (float*)outv + (size_t)n * D + lane * 8;
        *(float4*)(o + 0) = make_float4(r[0], r[1], r[2], r[3]);
        *(float4*)(o + 4) = make_float4(r[4], r[5], r[6], r[7]);
    }
}

__global__ void write_scalar_kernel(float* p, float v) { *p = v; }

// ------------------------------------------------ launch
extern "C" void kernel_launch(void* const* d_in, const int* in_sizes, int n_in,
                              void* d_out, int out_size, void* d_ws, size_t ws_size,
                              hipStream_t stream) {
    const float* features = (const float*)d_in[0];
    const int* edge_index = (const int*)d_in[1];
    const float* edge_w = (const float*)d_in[2];
    const float* W1 = (const float*)d_in[3];
    const float* b1 = (const float*)d_in[4];
    const float* W2 = (const float*)d_in[5];
    const float* b2 = (const float*)d_in[6];
    const int* src = edge_index;        // edge_index[0]
    const int* dst = edge_index + NE;   // edge_index[1]

    char* ws = (char*)d_ws;
    auto carve = [&](size_t bytes) {
        char* p = ws;
        ws += (bytes + 255) & ~(size_t)255;
        return p;
    };
    int* cnt = (int*)carve((size_t)NN * 4);
    int* row_ptr = (int*)carve((size_t)(NN + 1) * 4);
    int* cursor = (int*)carve((size_t)NN * 4);
    int* partial = (int*)carve((size_t)SCAN_NB * 4);
    int* pexcl = (int*)carve((size_t)SCAN_NB * 4);
    unsigned* erec = (unsigned*)carve((size_t)NE * 4);
    float* degw = (float*)carve((size_t)NN * 4);
    float* cvec = (float*)carve((size_t)64 * 4);
    unsigned short* W12T = (unsigned short*)carve((size_t)64 * 256 * 2);
    unsigned short* z_bf = (unsigned short*)carve((size_t)NN * 64 * 2);
    unsigned short* p1_bf = (unsigned short*)carve((size_t)NN * 64 * 2);
    unsigned short* h_bf = (unsigned short*)carve((size_t)NN * 64 * 2);
    unsigned short* xb0 = (unsigned short*)carve((size_t)NN * 64 * 2);
    unsigned short* xb1 = (unsigned short*)carve((size_t)NN * 64 * 2);

    const int EB4 = (NE / 4 + 255) / 256;
    const int PB = (NN + 31) / 32;   // prop blocks (32 nodes each)

    // ---- K1: {edge count (fire-forget atomics), W12T, cvec} ----
    hipMemsetAsync(cnt, 0, (size_t)NN * 4, stream);
    fused_pre_kernel<<<CNT_NB + 64 + 1, 256, 0, stream>>>(dst, cnt, W1, W2, W12T,
                                                          b1, cvec);

    // ---- K2: {block scan of cnt, z = F @ W12 GEMM} ----
    fused_scan_gemm_kernel<<<SCAN_NB + GEMM_NB, 256, 0, stream>>>(
        cnt, row_ptr, partial, features, W12T, z_bf);

    // ---- scan finish + cursor init ----
    scan_partials_kernel<<<1, 256, 0, stream>>>(partial, pexcl, row_ptr, SCAN_NB);
    scan_add_cursor_kernel<<<SCAN_NB, 256, 0, stream>>>(row_ptr, pexcl, cursor, NN);

    // ---- CSR fill (cursor atomics) ----
    fill_kernel<<<EB4, 256, 0, stream>>>(src, dst, edge_w, cursor, erec);

    // ---- p1 = prop(z) [+degw];  h = prop(p1) + degw*c + b2 ----
    prop_kernel<0, true, true><<<PB, 256, 0, stream>>>(row_ptr, erec, z_bf, nullptr,
                                                       nullptr, degw, nullptr,
                                                       p1_bf);
    prop_kernel<2, true, false><<<PB, 256, 0, stream>>>(row_ptr, erec, p1_bf, cvec,
                                                        b2, degw, nullptr, h_bf);

    // ---- APPNP: 10 steps of x = 0.9*prop(x) + 0.1*h ----
    const unsigned short* x_cur = h_bf;
    for (int k = 0; k < 9; ++k) {
        unsigned short* out = (k & 1) ? xb1 : xb0;
        prop_kernel<1, true, false><<<PB, 256, 0, stream>>>(row_ptr, erec, x_cur,
                                                            nullptr, nullptr,
                                                            nullptr, h_bf, out);
        x_cur = out;
    }
    prop_kernel<1, false, false><<<PB, 256, 0, stream>>>(row_ptr, erec, x_cur,
                                                         nullptr, nullptr, nullptr,
                                                         h_bf, (float*)d_out);

    // ---- second tuple element: the Python int 10 ----
    if (out_size > NN * 64) {
        write_scalar_kernel<<<1, 1, 0, stream>>>((float*)d_out + (size_t)NN * 64,
                                                 10.0f);
    }
}

// Round 5
// 347.615 us; speedup vs baseline: 1.4852x; 1.0968x over previous
//
#include <hip/hip_runtime.h>

#define NN 50000
#define NE 800000
#define SCAN_NB ((NN + 255) / 256)
#define GEMM_NB ((NN + 63) / 64)
#define CNT_NB ((NE / 8 + 255) / 256)

typedef short bf16x8 __attribute__((ext_vector_type(8)));
typedef float f32x4 __attribute__((ext_vector_type(4)));
typedef unsigned u32x4 __attribute__((ext_vector_type(4)));

// ------------------------------------------------ bf16 helpers (ushort = bf16)
__device__ inline void bf16x8_to_f32(const u32x4 v, float* f) {
    f[0] = __uint_as_float(v.x << 16);
    f[1] = __uint_as_float(v.x & 0xffff0000u);
    f[2] = __uint_as_float(v.y << 16);
    f[3] = __uint_as_float(v.y & 0xffff0000u);
    f[4] = __uint_as_float(v.z << 16);
    f[5] = __uint_as_float(v.z & 0xffff0000u);
    f[6] = __uint_as_float(v.w << 16);
    f[7] = __uint_as_float(v.w & 0xffff0000u);
}

__device__ inline unsigned f32_to_bf16(float x) {  // RTNE
    unsigned u = __float_as_uint(x);
    return (u + 0x7fffu + ((u >> 16) & 1u)) >> 16;
}

__device__ inline u32x4 f32x8_to_bf16(const float* f) {
    u32x4 v;
    v.x = f32_to_bf16(f[0]) | (f32_to_bf16(f[1]) << 16);
    v.y = f32_to_bf16(f[2]) | (f32_to_bf16(f[3]) << 16);
    v.z = f32_to_bf16(f[4]) | (f32_to_bf16(f[5]) << 16);
    v.w = f32_to_bf16(f[6]) | (f32_to_bf16(f[7]) << 16);
    return v;
}

// ================================================ K1: fused {hist+rank, W12T, cvec}
// hist: atomic-with-return (the unavoidable ~40us coherence-service cost, paid ONCE)
// w12t: W12T[n][k] = sum_j W1[k][j]*W2[j][n]   (64x256 bf16)
// cvec: c[d] = sum_k b1[k]*W2[k][d]
__global__ __launch_bounds__(256) void fused_pre_kernel(
    const int* __restrict__ dst, int* __restrict__ cnt, int* __restrict__ rank,
    const float* __restrict__ W1, const float* __restrict__ W2,
    unsigned short* __restrict__ W12T, const float* __restrict__ b1,
    float* __restrict__ cvec) {
    const int b = blockIdx.x;
    if (b < CNT_NB) {
        int i = (b * 256 + threadIdx.x) * 8;
        if (i < NE) {  // NE % 8 == 0
            int4 d0 = *(const int4*)(dst + i);
            int4 d1 = *(const int4*)(dst + i + 4);
            int4 r0, r1;
            r0.x = atomicAdd(&cnt[d0.x], 1);
            r0.y = atomicAdd(&cnt[d0.y], 1);
            r0.z = atomicAdd(&cnt[d0.z], 1);
            r0.w = atomicAdd(&cnt[d0.w], 1);
            r1.x = atomicAdd(&cnt[d1.x], 1);
            r1.y = atomicAdd(&cnt[d1.y], 1);
            r1.z = atomicAdd(&cnt[d1.z], 1);
            r1.w = atomicAdd(&cnt[d1.w], 1);
            *(int4*)(rank + i) = r0;
            *(int4*)(rank + i + 4) = r1;
        }
    } else if (b < CNT_NB + 64) {
        int i = (b - CNT_NB) * 256 + threadIdx.x;  // i = n*256 + k, n<64, k<256
        int n = i >> 8, k = i & 255;
        float s = 0.f;
        for (int j = 0; j < 128; ++j)
            s += W1[(size_t)k * 128 + j] * W2[(size_t)j * 64 + n];
        W12T[i] = (unsigned short)f32_to_bf16(s);
    } else {
        int d = threadIdx.x;
        if (d < 64) {
            float s = 0.f;
            for (int k = 0; k < 128; ++k) s += b1[k] * W2[(size_t)k * 64 + d];
            cvec[d] = s;
        }
    }
}

// ================================================ K2: fused {scan_block, MFMA GEMM}
__global__ __launch_bounds__(256) void fused_scan_gemm_kernel(
    const int* __restrict__ cnt, int* __restrict__ row_ptr,
    int* __restrict__ partial, const float* __restrict__ A,
    const unsigned short* __restrict__ BT, unsigned short* __restrict__ C) {
    __shared__ int wsums[4];
    __shared__ unsigned short As[64][40];
    __shared__ unsigned short Bs[64][40];

    if (blockIdx.x < SCAN_NB) {
        int i = blockIdx.x * 256 + threadIdx.x;
        int v = (i < NN) ? cnt[i] : 0;
        const int lane = threadIdx.x & 63;
        const int wid = threadIdx.x >> 6;
        int incl = v;
        #pragma unroll
        for (int off = 1; off < 64; off <<= 1) {
            int t = __shfl_up(incl, off);
            if (lane >= off) incl += t;
        }
        if (lane == 63) wsums[wid] = incl;
        __syncthreads();
        int woff = 0;
        #pragma unroll
        for (int w = 0; w < 4; ++w)
            if (w < wid) woff += wsums[w];
        if (i < NN) row_ptr[i] = woff + incl - v;
        if (threadIdx.x == 0)
            partial[blockIdx.x] = wsums[0] + wsums[1] + wsums[2] + wsums[3];
        return;
    }

    constexpr int N = 64, K = 256;
    constexpr int NT = N / 16;
    constexpr int KS = K / 32;
    const int tid = threadIdx.x;
    const int wave = tid >> 6;
    const int lane = tid & 63;
    const int lm = lane & 15;
    const int lq = lane >> 4;
    const int row0 = (blockIdx.x - SCAN_NB) * 64;
    const int m0 = wave * 16;

    f32x4 acc[NT] = {};

    for (int ks = 0; ks < KS; ++ks) {
        const int k0 = ks * 32;
        {
            int m = tid >> 2, kc = (tid & 3) * 8;
            int gm = row0 + m;
            if (gm >= NN) gm = NN - 1;
            float4 v0 = *(const float4*)(A + (size_t)gm * K + k0 + kc);
            float4 v1 = *(const float4*)(A + (size_t)gm * K + k0 + kc + 4);
            float f[8] = {v0.x, v0.y, v0.z, v0.w, v1.x, v1.y, v1.z, v1.w};
            *(u32x4*)&As[m][kc] = f32x8_to_bf16(f);
        }
        #pragma unroll
        for (int c = tid; c < N * 4; c += 256) {
            int n = c >> 2, kc = (c & 3) * 8;
            *(uint4*)&Bs[n][kc] = *(const uint4*)(BT + (size_t)n * K + k0 + kc);
        }
        __syncthreads();
        bf16x8 a = *(const bf16x8*)&As[m0 + lm][lq * 8];
        #pragma unroll
        for (int t = 0; t < NT; ++t) {
            bf16x8 b = *(const bf16x8*)&Bs[t * 16 + lm][lq * 8];
            acc[t] = __builtin_amdgcn_mfma_f32_16x16x32_bf16(a, b, acc[t], 0, 0, 0);
        }
        __syncthreads();
    }
    #pragma unroll
    for (int r = 0; r < 4; ++r) {
        int gm = row0 + m0 + lq * 4 + r;
        if (gm < NN) {
            #pragma unroll
            for (int t = 0; t < NT; ++t)
                C[(size_t)gm * N + t * 16 + lm] =
                    (unsigned short)f32_to_bf16(acc[t][r]);
        }
    }
}

// ------------------------------------------------ scan of per-block partials
__global__ __launch_bounds__(256) void scan_partials_kernel(int* __restrict__ partial,
                                                            int* __restrict__ pexcl,
                                                            int* __restrict__ row_ptr,
                                                            int np) {
    __shared__ int wsums[4];
    int v = (threadIdx.x < np) ? partial[threadIdx.x] : 0;
    const int lane = threadIdx.x & 63;
    const int wid = threadIdx.x >> 6;
    int incl = v;
    #pragma unroll
    for (int off = 1; off < 64; off <<= 1) {
        int t = __shfl_up(incl, off);
        if (lane >= off) incl += t;
    }
    if (lane == 63) wsums[wid] = incl;
    __syncthreads();
    int woff = 0;
    #pragma unroll
    for (int w = 0; w < 4; ++w)
        if (w < wid) woff += wsums[w];
    if (threadIdx.x < np) pexcl[threadIdx.x] = woff + incl - v;
    if (threadIdx.x == 0) row_ptr[NN] = NE;
}

__global__ __launch_bounds__(256) void scan_add_kernel(int* __restrict__ row_ptr,
                                                       const int* __restrict__ pexcl,
                                                       int n) {
    int i = blockIdx.x * 256 + threadIdx.x;
    if (i < n) row_ptr[i] += pexcl[blockIdx.x];
}

// ------------------------------------------------ CSR fill (atomic-free, 4B rec)
__global__ __launch_bounds__(256) void fill_kernel(const int* __restrict__ src,
                                                   const int* __restrict__ dst,
                                                   const float* __restrict__ w,
                                                   const int* __restrict__ row_ptr,
                                                   const int* __restrict__ rank,
                                                   unsigned* __restrict__ er) {
    int i = (blockIdx.x * 256 + threadIdx.x) * 4;
    if (i < NE) {  // NE % 4 == 0
        int4 d = *(const int4*)(dst + i);
        int4 s = *(const int4*)(src + i);
        int4 rk = *(const int4*)(rank + i);
        float4 wv = *(const float4*)(w + i);
        er[row_ptr[d.x] + rk.x] = (f32_to_bf16(wv.x) << 16) | (unsigned)s.x;
        er[row_ptr[d.y] + rk.y] = (f32_to_bf16(wv.y) << 16) | (unsigned)s.y;
        er[row_ptr[d.z] + rk.z] = (f32_to_bf16(wv.z) << 16) | (unsigned)s.z;
        er[row_ptr[d.w] + rk.w] = (f32_to_bf16(wv.w) << 16) | (unsigned)s.w;
    }
}

// ------------------------------------------------ propagation D=64 (bf16, 4B rec)
// rec = bf16(w)<<16 | src (src < 65536 since NN=50000).
// Unroll-8 main loop: 8 independent gathers in flight per wave (~128 lines)
// to saturate per-CU outstanding-miss capacity.
// MODE 0: out = acc                         (conv1-fused; DEGW: also sum w)
// MODE 2: out = acc + degw[n]*c[d] + b2[d]  (conv2 epilogue)
// MODE 1: out = 0.9*acc + 0.1*h[n][d]       (APPNP step)
template <int MODE, bool OUT_BF16, bool DEGW>
__global__ __launch_bounds__(256, 4) void prop_kernel(
    const int* __restrict__ row_ptr, const unsigned* __restrict__ er,
    const unsigned short* __restrict__ x, const float* __restrict__ cvec,
    const float* __restrict__ b2, float* __restrict__ degw,
    const unsigned short* __restrict__ hbf, void* __restrict__ outv) {
    constexpr int D = 64;
    const int local = threadIdx.x >> 3;     // node within block (32/block)
    const int lane = threadIdx.x & 7;       // 8 threads/node, 16B each
    const int n = blockIdx.x * 32 + local;
    if (n >= NN) return;

    int e = row_ptr[n];
    const int end = row_ptr[n + 1];

    float acc[8] = {};
    float sw = 0.f;
    float f[8];

    for (; e + 7 < end; e += 8) {
        unsigned rr[8];
        #pragma unroll
        for (int q = 0; q < 8; ++q) rr[q] = er[e + q];
        u32x4 uu[8];
        #pragma unroll
        for (int q = 0; q < 8; ++q)
            uu[q] = *(const u32x4*)(x + (size_t)(rr[q] & 0xffffu) * D + lane * 8);
        #pragma unroll
        for (int q = 0; q < 8; ++q) {
            float wq = __uint_as_float(rr[q] & 0xffff0000u);
            if (DEGW) sw += wq;
            bf16x8_to_f32(uu[q], f);
            #pragma unroll
            for (int j = 0; j < 8; ++j) acc[j] += wq * f[j];
        }
    }
    for (; e + 3 < end; e += 4) {
        unsigned rr[4];
        #pragma unroll
        for (int q = 0; q < 4; ++q) rr[q] = er[e + q];
        u32x4 uu[4];
        #pragma unroll
        for (int q = 0; q < 4; ++q)
            uu[q] = *(const u32x4*)(x + (size_t)(rr[q] & 0xffffu) * D + lane * 8);
        #pragma unroll
        for (int q = 0; q < 4; ++q) {
            float wq = __uint_as_float(rr[q] & 0xffff0000u);
            if (DEGW) sw += wq;
            bf16x8_to_f32(uu[q], f);
            #pragma unroll
            for (int j = 0; j < 8; ++j) acc[j] += wq * f[j];
        }
    }
    for (; e < end; ++e) {
        unsigned r0 = er[e];
        u32x4 u0 = *(const u32x4*)(x + (size_t)(r0 & 0xffffu) * D + lane * 8);
        float w0 = __uint_as_float(r0 & 0xffff0000u);
        if (DEGW) sw += w0;
        bf16x8_to_f32(u0, f);
        #pragma unroll
        for (int j = 0; j < 8; ++j) acc[j] += w0 * f[j];
    }

    if (DEGW) {
        if (lane == 0) degw[n] = sw;
    }

    float r[8];
    if (MODE == 0) {
        #pragma unroll
        for (int j = 0; j < 8; ++j) r[j] = acc[j];
    } else if (MODE == 2) {
        float dw = degw[n];
        #pragma unroll
        for (int j = 0; j < 8; ++j)
            r[j] = acc[j] + dw * cvec[lane * 8 + j] + b2[lane * 8 + j];
    } else {
        u32x4 uh = *(const u32x4*)(hbf + (size_t)n * D + lane * 8);
        float fh[8];
        bf16x8_to_f32(uh, fh);
        #pragma unroll
        for (int j = 0; j < 8; ++j) r[j] = 0.9f * acc[j] + 0.1f * fh[j];
    }

    if (OUT_BF16) {
        *(u32x4*)((unsigned short*)outv + (size_t)n * D + lane * 8) =
            f32x8_to_bf16(r);
    } else {
        float* o = (float*)outv + (size_t)n * D + lane * 8;
        *(float4*)(o + 0) = make_float4(r[0], r[1], r[2], r[3]);
        *(float4*)(o + 4) = make_float4(r[4], r[5], r[6], r[7]);
    }
}

__global__ void write_scalar_kernel(float* p, float v) { *p = v; }

// ------------------------------------------------ launch
extern "C" void kernel_launch(void* const* d_in, const int* in_sizes, int n_in,
                              void* d_out, int out_size, void* d_ws, size_t ws_size,
                              hipStream_t stream) {
    const float* features = (const float*)d_in[0];
    const int* edge_index = (const int*)d_in[1];
    const float* edge_w = (const float*)d_in[2];
    const float* W1 = (const float*)d_in[3];
    const float* b1 = (const float*)d_in[4];
    const float* W2 = (const float*)d_in[5];
    const float* b2 = (const float*)d_in[6];
    const int* src = edge_index;        // edge_index[0]
    const int* dst = edge_index + NE;   // edge_index[1]

    char* ws = (char*)d_ws;
    auto carve = [&](size_t bytes) {
        char* p = ws;
        ws += (bytes + 255) & ~(size_t)255;
        return p;
    };
    int* cnt = (int*)carve((size_t)NN * 4);
    int* rank = (int*)carve((size_t)NE * 4);
    int* row_ptr = (int*)carve((size_t)(NN + 1) * 4);
    int* partial = (int*)carve((size_t)SCAN_NB * 4);
    int* pexcl = (int*)carve((size_t)SCAN_NB * 4);
    unsigned* erec = (unsigned*)carve((size_t)NE * 4);
    float* degw = (float*)carve((size_t)NN * 4);
    float* cvec = (float*)carve((size_t)64 * 4);
    unsigned short* W12T = (unsigned short*)carve((size_t)64 * 256 * 2);
    unsigned short* z_bf = (unsigned short*)carve((size_t)NN * 64 * 2);
    unsigned short* p1_bf = (unsigned short*)carve((size_t)NN * 64 * 2);
    unsigned short* h_bf = (unsigned short*)carve((size_t)NN * 64 * 2);
    unsigned short* xb0 = (unsigned short*)carve((size_t)NN * 64 * 2);
    unsigned short* xb1 = (unsigned short*)carve((size_t)NN * 64 * 2);

    const int EB4 = (NE / 4 + 255) / 256;
    const int PB = (NN + 31) / 32;   // prop blocks (32 nodes each)

    // ---- K1: {hist+rank (atomic-return, once), W12T, cvec} ----
    hipMemsetAsync(cnt, 0, (size_t)NN * 4, stream);
    fused_pre_kernel<<<CNT_NB + 64 + 1, 256, 0, stream>>>(dst, cnt, rank, W1, W2,
                                                          W12T, b1, cvec);

    // ---- K2: {block scan of cnt, z = F @ W12 GEMM} ----
    fused_scan_gemm_kernel<<<SCAN_NB + GEMM_NB, 256, 0, stream>>>(
        cnt, row_ptr, partial, features, W12T, z_bf);

    // ---- scan finish ----
    scan_partials_kernel<<<1, 256, 0, stream>>>(partial, pexcl, row_ptr, SCAN_NB);
    scan_add_kernel<<<SCAN_NB, 256, 0, stream>>>(row_ptr, pexcl, NN);

    // ---- CSR fill (atomic-free) ----
    fill_kernel<<<EB4, 256, 0, stream>>>(src, dst, edge_w, row_ptr, rank, erec);

    // ---- p1 = prop(z) [+degw];  h = prop(p1) + degw*c + b2 ----
    prop_kernel<0, true, true><<<PB, 256, 0, stream>>>(row_ptr, erec, z_bf, nullptr,
                                                       nullptr, degw, nullptr,
                                                       p1_bf);
    prop_kernel<2, true, false><<<PB, 256, 0, stream>>>(row_ptr, erec, p1_bf, cvec,
                                                        b2, degw, nullptr, h_bf);

    // ---- APPNP: 10 steps of x = 0.9*prop(x) + 0.1*h ----
    const unsigned short* x_cur = h_bf;
    for (int k = 0; k < 9; ++k) {
        unsigned short* out = (k & 1) ? xb1 : xb0;
        prop_kernel<1, true, false><<<PB, 256, 0, stream>>>(row_ptr, erec, x_cur,
                                                            nullptr, nullptr,
                                                            nullptr, h_bf, out);
        x_cur = out;
    }
    prop_kernel<1, false, false><<<PB, 256, 0, stream>>>(row_ptr, erec, x_cur,
                                                         nullptr, nullptr, nullptr,
                                                         h_bf, (float*)d_out);

    // ---- second tuple element: the Python int 10 ----
    if (out_size > NN * 64) {
        write_scalar_kernel<<<1, 1, 0, stream>>>((float*)d_out + (size_t)NN * 64,
                                                 10.0f);
    }
}

// Round 6
// 346.400 us; speedup vs baseline: 1.4904x; 1.0035x over previous
//
#include <hip/hip_runtime.h>

#define NN 50000
#define NE 800000
#define SCAN_NB ((NN + 255) / 256)
#define GEMM_NB ((NN + 63) / 64)
#define CNT_NB ((NE / 8 + 255) / 256)

typedef short bf16x8 __attribute__((ext_vector_type(8)));
typedef float f32x4 __attribute__((ext_vector_type(4)));
typedef unsigned u32x4 __attribute__((ext_vector_type(4)));

// ------------------------------------------------ bf16 helpers (ushort = bf16)
__device__ inline void bf16x8_to_f32(const u32x4 v, float* f) {
    f[0] = __uint_as_float(v.x << 16);
    f[1] = __uint_as_float(v.x & 0xffff0000u);
    f[2] = __uint_as_float(v.y << 16);
    f[3] = __uint_as_float(v.y & 0xffff0000u);
    f[4] = __uint_as_float(v.z << 16);
    f[5] = __uint_as_float(v.z & 0xffff0000u);
    f[6] = __uint_as_float(v.w << 16);
    f[7] = __uint_as_float(v.w & 0xffff0000u);
}

__device__ inline unsigned f32_to_bf16(float x) {  // RTNE
    unsigned u = __float_as_uint(x);
    return (u + 0x7fffu + ((u >> 16) & 1u)) >> 16;
}

__device__ inline u32x4 f32x8_to_bf16(const float* f) {
    u32x4 v;
    v.x = f32_to_bf16(f[0]) | (f32_to_bf16(f[1]) << 16);
    v.y = f32_to_bf16(f[2]) | (f32_to_bf16(f[3]) << 16);
    v.z = f32_to_bf16(f[4]) | (f32_to_bf16(f[5]) << 16);
    v.w = f32_to_bf16(f[6]) | (f32_to_bf16(f[7]) << 16);
    return v;
}

// ================================================ K1: fused {hist+rank, W12T, cvec, scalar}
// hist: atomic-with-return (the unavoidable ~40us coherence-service cost, paid ONCE)
// w12t: W12T[n][k] = sum_j W1[k][j]*W2[j][n]   (64x256 bf16)
// cvec: c[d] = sum_k b1[k]*W2[k][d]
__global__ __launch_bounds__(256) void fused_pre_kernel(
    const int* __restrict__ dst, int* __restrict__ cnt, int* __restrict__ rank,
    const float* __restrict__ W1, const float* __restrict__ W2,
    unsigned short* __restrict__ W12T, const float* __restrict__ b1,
    float* __restrict__ cvec, float* __restrict__ scalar_slot) {
    const int b = blockIdx.x;
    if (b < CNT_NB) {
        int i = (b * 256 + threadIdx.x) * 8;
        if (i < NE) {  // NE % 8 == 0
            int4 d0 = *(const int4*)(dst + i);
            int4 d1 = *(const int4*)(dst + i + 4);
            int4 r0, r1;
            r0.x = atomicAdd(&cnt[d0.x], 1);
            r0.y = atomicAdd(&cnt[d0.y], 1);
            r0.z = atomicAdd(&cnt[d0.z], 1);
            r0.w = atomicAdd(&cnt[d0.w], 1);
            r1.x = atomicAdd(&cnt[d1.x], 1);
            r1.y = atomicAdd(&cnt[d1.y], 1);
            r1.z = atomicAdd(&cnt[d1.z], 1);
            r1.w = atomicAdd(&cnt[d1.w], 1);
            *(int4*)(rank + i) = r0;
            *(int4*)(rank + i + 4) = r1;
        }
    } else if (b < CNT_NB + 64) {
        int i = (b - CNT_NB) * 256 + threadIdx.x;  // i = n*256 + k, n<64, k<256
        int n = i >> 8, k = i & 255;
        float s = 0.f;
        for (int j = 0; j < 128; ++j)
            s += W1[(size_t)k * 128 + j] * W2[(size_t)j * 64 + n];
        W12T[i] = (unsigned short)f32_to_bf16(s);
    } else {
        int d = threadIdx.x;
        if (d < 64) {
            float s = 0.f;
            for (int k = 0; k < 128; ++k) s += b1[k] * W2[(size_t)k * 64 + d];
            cvec[d] = s;
        }
        if (threadIdx.x == 64 && scalar_slot) *scalar_slot = 10.0f;
    }
}

// ================================================ K2: fused {scan_block, MFMA GEMM}
__global__ __launch_bounds__(256) void fused_scan_gemm_kernel(
    const int* __restrict__ cnt, int* __restrict__ row_ptr,
    int* __restrict__ partial, const float* __restrict__ A,
    const unsigned short* __restrict__ BT, unsigned short* __restrict__ C) {
    __shared__ int wsums[4];
    __shared__ unsigned short As[64][40];
    __shared__ unsigned short Bs[64][40];

    if (blockIdx.x < SCAN_NB) {
        int i = blockIdx.x * 256 + threadIdx.x;
        int v = (i < NN) ? cnt[i] : 0;
        const int lane = threadIdx.x & 63;
        const int wid = threadIdx.x >> 6;
        int incl = v;
        #pragma unroll
        for (int off = 1; off < 64; off <<= 1) {
            int t = __shfl_up(incl, off);
            if (lane >= off) incl += t;
        }
        if (lane == 63) wsums[wid] = incl;
        __syncthreads();
        int woff = 0;
        #pragma unroll
        for (int w = 0; w < 4; ++w)
            if (w < wid) woff += wsums[w];
        if (i < NN) row_ptr[i] = woff + incl - v;
        if (threadIdx.x == 0)
            partial[blockIdx.x] = wsums[0] + wsums[1] + wsums[2] + wsums[3];
        return;
    }

    constexpr int N = 64, K = 256;
    constexpr int NT = N / 16;
    constexpr int KS = K / 32;
    const int tid = threadIdx.x;
    const int wave = tid >> 6;
    const int lane = tid & 63;
    const int lm = lane & 15;
    const int lq = lane >> 4;
    const int row0 = (blockIdx.x - SCAN_NB) * 64;
    const int m0 = wave * 16;

    f32x4 acc[NT] = {};

    for (int ks = 0; ks < KS; ++ks) {
        const int k0 = ks * 32;
        {
            int m = tid >> 2, kc = (tid & 3) * 8;
            int gm = row0 + m;
            if (gm >= NN) gm = NN - 1;
            float4 v0 = *(const float4*)(A + (size_t)gm * K + k0 + kc);
            float4 v1 = *(const float4*)(A + (size_t)gm * K + k0 + kc + 4);
            float f[8] = {v0.x, v0.y, v0.z, v0.w, v1.x, v1.y, v1.z, v1.w};
            *(u32x4*)&As[m][kc] = f32x8_to_bf16(f);
        }
        #pragma unroll
        for (int c = tid; c < N * 4; c += 256) {
            int n = c >> 2, kc = (c & 3) * 8;
            *(uint4*)&Bs[n][kc] = *(const uint4*)(BT + (size_t)n * K + k0 + kc);
        }
        __syncthreads();
        bf16x8 a = *(const bf16x8*)&As[m0 + lm][lq * 8];
        #pragma unroll
        for (int t = 0; t < NT; ++t) {
            bf16x8 b = *(const bf16x8*)&Bs[t * 16 + lm][lq * 8];
            acc[t] = __builtin_amdgcn_mfma_f32_16x16x32_bf16(a, b, acc[t], 0, 0, 0);
        }
        __syncthreads();
    }
    #pragma unroll
    for (int r = 0; r < 4; ++r) {
        int gm = row0 + m0 + lq * 4 + r;
        if (gm < NN) {
            #pragma unroll
            for (int t = 0; t < NT; ++t)
                C[(size_t)gm * N + t * 16 + lm] =
                    (unsigned short)f32_to_bf16(acc[t][r]);
        }
    }
}

// ------------------------------------------------ scan of per-block partials
__global__ __launch_bounds__(256) void scan_partials_kernel(int* __restrict__ partial,
                                                            int* __restrict__ pexcl,
                                                            int* __restrict__ row_ptr,
                                                            int np) {
    __shared__ int wsums[4];
    int v = (threadIdx.x < np) ? partial[threadIdx.x] : 0;
    const int lane = threadIdx.x & 63;
    const int wid = threadIdx.x >> 6;
    int incl = v;
    #pragma unroll
    for (int off = 1; off < 64; off <<= 1) {
        int t = __shfl_up(incl, off);
        if (lane >= off) incl += t;
    }
    if (lane == 63) wsums[wid] = incl;
    __syncthreads();
    int woff = 0;
    #pragma unroll
    for (int w = 0; w < 4; ++w)
        if (w < wid) woff += wsums[w];
    if (threadIdx.x < np) pexcl[threadIdx.x] = woff + incl - v;
    if (threadIdx.x == 0) row_ptr[NN] = NE;
}

__global__ __launch_bounds__(256) void scan_add_kernel(int* __restrict__ row_ptr,
                                                       const int* __restrict__ pexcl,
                                                       int n) {
    int i = blockIdx.x * 256 + threadIdx.x;
    if (i < n) row_ptr[i] += pexcl[blockIdx.x];
}

// ------------------------------------------------ CSR fill (atomic-free, 4B rec)
__global__ __launch_bounds__(256) void fill_kernel(const int* __restrict__ src,
                                                   const int* __restrict__ dst,
                                                   const float* __restrict__ w,
                                                   const int* __restrict__ row_ptr,
                                                   const int* __restrict__ rank,
                                                   unsigned* __restrict__ er) {
    int i = (blockIdx.x * 256 + threadIdx.x) * 4;
    if (i < NE) {  // NE % 4 == 0
        int4 d = *(const int4*)(dst + i);
        int4 s = *(const int4*)(src + i);
        int4 rk = *(const int4*)(rank + i);
        float4 wv = *(const float4*)(w + i);
        er[row_ptr[d.x] + rk.x] = (f32_to_bf16(wv.x) << 16) | (unsigned)s.x;
        er[row_ptr[d.y] + rk.y] = (f32_to_bf16(wv.y) << 16) | (unsigned)s.y;
        er[row_ptr[d.z] + rk.z] = (f32_to_bf16(wv.z) << 16) | (unsigned)s.z;
        er[row_ptr[d.w] + rk.w] = (f32_to_bf16(wv.w) << 16) | (unsigned)s.w;
    }
}

// ------------------------------------------------ propagation D=64 (bf16, 4B rec)
// rec = bf16(w)<<16 | src (src < 65536 since NN=50000).
// Unroll-8 main loop. er records are loaded ONCE per group (lane j loads er[e+j])
// and broadcast via __shfl — halves the VMEM request stream vs redundant loads.
// MODE 0: out = acc                         (conv1-fused; DEGW: also sum w)
// MODE 2: out = acc + degw[n]*c[d] + b2[d]  (conv2 epilogue)
// MODE 1: out = 0.9*acc + 0.1*h[n][d]       (APPNP step)
template <int MODE, bool OUT_BF16, bool DEGW>
__global__ __launch_bounds__(256, 4) void prop_kernel(
    const int* __restrict__ row_ptr, const unsigned* __restrict__ er,
    const unsigned short* __restrict__ x, const float* __restrict__ cvec,
    const float* __restrict__ b2, float* __restrict__ degw,
    const unsigned short* __restrict__ hbf, void* __restrict__ outv) {
    constexpr int D = 64;
    const int local = threadIdx.x >> 3;     // node within block (32/block)
    const int lane = threadIdx.x & 7;       // 8 threads/node, 16B each
    const int wbase = threadIdx.x & 56;     // group base lane within wave
    const int n = blockIdx.x * 32 + local;
    if (n >= NN) return;

    int e = row_ptr[n];
    const int end = row_ptr[n + 1];

    float acc[8] = {};
    float sw = 0.f;
    float f[8];

    for (; e + 7 < end; e += 8) {
        // one er load per lane covers the group's 8 records; broadcast via shfl
        unsigned rq = er[e + lane];
        unsigned rr[8];
        #pragma unroll
        for (int q = 0; q < 8; ++q) rr[q] = __shfl(rq, wbase + q, 64);
        u32x4 uu[8];
        #pragma unroll
        for (int q = 0; q < 8; ++q)
            uu[q] = *(const u32x4*)(x + (size_t)(rr[q] & 0xffffu) * D + lane * 8);
        #pragma unroll
        for (int q = 0; q < 8; ++q) {
            float wq = __uint_as_float(rr[q] & 0xffff0000u);
            if (DEGW) sw += wq;
            bf16x8_to_f32(uu[q], f);
            #pragma unroll
            for (int j = 0; j < 8; ++j) acc[j] += wq * f[j];
        }
    }
    for (; e + 3 < end; e += 4) {
        unsigned rr[4];
        #pragma unroll
        for (int q = 0; q < 4; ++q) rr[q] = er[e + q];
        u32x4 uu[4];
        #pragma unroll
        for (int q = 0; q < 4; ++q)
            uu[q] = *(const u32x4*)(x + (size_t)(rr[q] & 0xffffu) * D + lane * 8);
        #pragma unroll
        for (int q = 0; q < 4; ++q) {
            float wq = __uint_as_float(rr[q] & 0xffff0000u);
            if (DEGW) sw += wq;
            bf16x8_to_f32(uu[q], f);
            #pragma unroll
            for (int j = 0; j < 8; ++j) acc[j] += wq * f[j];
        }
    }
    for (; e < end; ++e) {
        unsigned r0 = er[e];
        u32x4 u0 = *(const u32x4*)(x + (size_t)(r0 & 0xffffu) * D + lane * 8);
        float w0 = __uint_as_float(r0 & 0xffff0000u);
        if (DEGW) sw += w0;
        bf16x8_to_f32(u0, f);
        #pragma unroll
        for (int j = 0; j < 8; ++j) acc[j] += w0 * f[j];
    }

    if (DEGW) {
        if (lane == 0) degw[n] = sw;
    }

    float r[8];
    if (MODE == 0) {
        #pragma unroll
        for (int j = 0; j < 8; ++j) r[j] = acc[j];
    } else if (MODE == 2) {
        float dw = degw[n];
        #pragma unroll
        for (int j = 0; j < 8; ++j)
            r[j] = acc[j] + dw * cvec[lane * 8 + j] + b2[lane * 8 + j];
    } else {
        u32x4 uh = *(const u32x4*)(hbf + (size_t)n * D + lane * 8);
        float fh[8];
        bf16x8_to_f32(uh, fh);
        #pragma unroll
        for (int j = 0; j < 8; ++j) r[j] = 0.9f * acc[j] + 0.1f * fh[j];
    }

    if (OUT_BF16) {
        *(u32x4*)((unsigned short*)outv + (size_t)n * D + lane * 8) =
            f32x8_to_bf16(r);
    } else {
        float* o = (float*)outv + (size_t)n * D + lane * 8;
        *(float4*)(o + 0) = make_float4(r[0], r[1], r[2], r[3]);
        *(float4*)(o + 4) = make_float4(r[4], r[5], r[6], r[7]);
    }
}

// ------------------------------------------------ launch
extern "C" void kernel_launch(void* const* d_in, const int* in_sizes, int n_in,
                              void* d_out, int out_size, void* d_ws, size_t ws_size,
                              hipStream_t stream) {
    const float* features = (const float*)d_in[0];
    const int* edge_index = (const int*)d_in[1];
    const float* edge_w = (const float*)d_in[2];
    const float* W1 = (const float*)d_in[3];
    const float* b1 = (const float*)d_in[4];
    const float* W2 = (const float*)d_in[5];
    const float* b2 = (const float*)d_in[6];
    const int* src = edge_index;        // edge_index[0]
    const int* dst = edge_index + NE;   // edge_index[1]

    char* ws = (char*)d_ws;
    auto carve = [&](size_t bytes) {
        char* p = ws;
        ws += (bytes + 255) & ~(size_t)255;
        return p;
    };
    int* cnt = (int*)carve((size_t)NN * 4);
    int* rank = (int*)carve((size_t)NE * 4);
    int* row_ptr = (int*)carve((size_t)(NN + 1) * 4);
    int* partial = (int*)carve((size_t)SCAN_NB * 4);
    int* pexcl = (int*)carve((size_t)SCAN_NB * 4);
    unsigned* erec = (unsigned*)carve((size_t)NE * 4);
    float* degw = (float*)carve((size_t)NN * 4);
    float* cvec = (float*)carve((size_t)64 * 4);
    unsigned short* W12T = (unsigned short*)carve((size_t)64 * 256 * 2);
    unsigned short* z_bf = (unsigned short*)carve((size_t)NN * 64 * 2);
    unsigned short* p1_bf = (unsigned short*)carve((size_t)NN * 64 * 2);
    unsigned short* h_bf = (unsigned short*)carve((size_t)NN * 64 * 2);
    unsigned short* xb0 = (unsigned short*)carve((size_t)NN * 64 * 2);
    unsigned short* xb1 = (unsigned short*)carve((size_t)NN * 64 * 2);

    const int EB4 = (NE / 4 + 255) / 256;
    const int PB = (NN + 31) / 32;   // prop blocks (32 nodes each)

    float* scalar_slot =
        (out_size > NN * 64) ? ((float*)d_out + (size_t)NN * 64) : nullptr;

    // ---- K1: {hist+rank (atomic-return, once), W12T, cvec, out scalar} ----
    hipMemsetAsync(cnt, 0, (size_t)NN * 4, stream);
    fused_pre_kernel<<<CNT_NB + 64 + 1, 256, 0, stream>>>(dst, cnt, rank, W1, W2,
                                                          W12T, b1, cvec,
                                                          scalar_slot);

    // ---- K2: {block scan of cnt, z = F @ W12 GEMM} ----
    fused_scan_gemm_kernel<<<SCAN_NB + GEMM_NB, 256, 0, stream>>>(
        cnt, row_ptr, partial, features, W12T, z_bf);

    // ---- scan finish ----
    scan_partials_kernel<<<1, 256, 0, stream>>>(partial, pexcl, row_ptr, SCAN_NB);
    scan_add_kernel<<<SCAN_NB, 256, 0, stream>>>(row_ptr, pexcl, NN);

    // ---- CSR fill (atomic-free) ----
    fill_kernel<<<EB4, 256, 0, stream>>>(src, dst, edge_w, row_ptr, rank, erec);

    // ---- p1 = prop(z) [+degw];  h = prop(p1) + degw*c + b2 ----
    prop_kernel<0, true, true><<<PB, 256, 0, stream>>>(row_ptr, erec, z_bf, nullptr,
                                                       nullptr, degw, nullptr,
                                                       p1_bf);
    prop_kernel<2, true, false><<<PB, 256, 0, stream>>>(row_ptr, erec, p1_bf, cvec,
                                                        b2, degw, nullptr, h_bf);

    // ---- APPNP: 10 steps of x = 0.9*prop(x) + 0.1*h ----
    const unsigned short* x_cur = h_bf;
    for (int k = 0; k < 9; ++k) {
        unsigned short* out = (k & 1) ? xb1 : xb0;
        prop_kernel<1, true, false><<<PB, 256, 0, stream>>>(row_ptr, erec, x_cur,
                                                            nullptr, nullptr,
                                                            nullptr, h_bf, out);
        x_cur = out;
    }
    prop_kernel<1, false, false><<<PB, 256, 0, stream>>>(row_ptr, erec, x_cur,
                                                         nullptr, nullptr, nullptr,
                                                         h_bf, (float*)d_out);
}

// Round 7
// 345.583 us; speedup vs baseline: 1.4940x; 1.0024x over previous
//
#include <hip/hip_runtime.h>

#define NN 50000
#define NE 800000
#define SCAN_NB ((NN + 255) / 256)
#define GEMM_NB ((NN + 63) / 64)
#define CNT_NB ((NE / 8 + 255) / 256)
#define CPAD 16  // one counter per 64B line: cnt16[n*CPAD]

typedef short bf16x8 __attribute__((ext_vector_type(8)));
typedef float f32x4 __attribute__((ext_vector_type(4)));
typedef unsigned u32x4 __attribute__((ext_vector_type(4)));

// ------------------------------------------------ bf16 helpers (ushort = bf16)
__device__ inline void bf16x8_to_f32(const u32x4 v, float* f) {
    f[0] = __uint_as_float(v.x << 16);
    f[1] = __uint_as_float(v.x & 0xffff0000u);
    f[2] = __uint_as_float(v.y << 16);
    f[3] = __uint_as_float(v.y & 0xffff0000u);
    f[4] = __uint_as_float(v.z << 16);
    f[5] = __uint_as_float(v.z & 0xffff0000u);
    f[6] = __uint_as_float(v.w << 16);
    f[7] = __uint_as_float(v.w & 0xffff0000u);
}

__device__ inline unsigned f32_to_bf16(float x) {  // RTNE
    unsigned u = __float_as_uint(x);
    return (u + 0x7fffu + ((u >> 16) & 1u)) >> 16;
}

__device__ inline u32x4 f32x8_to_bf16(const float* f) {
    u32x4 v;
    v.x = f32_to_bf16(f[0]) | (f32_to_bf16(f[1]) << 16);
    v.y = f32_to_bf16(f[2]) | (f32_to_bf16(f[3]) << 16);
    v.z = f32_to_bf16(f[4]) | (f32_to_bf16(f[5]) << 16);
    v.w = f32_to_bf16(f[6]) | (f32_to_bf16(f[7]) << 16);
    return v;
}

// ================================================ K0: {W12T, cvec, out scalar}
// w12t: W12T[n][k] = sum_j W1[k][j]*W2[j][n]   (64x256 bf16)
// cvec: c[d] = sum_k b1[k]*W2[k][d]
__global__ __launch_bounds__(256) void prep_kernel(
    const float* __restrict__ W1, const float* __restrict__ W2,
    unsigned short* __restrict__ W12T, const float* __restrict__ b1,
    float* __restrict__ cvec, float* __restrict__ scalar_slot) {
    const int b = blockIdx.x;
    if (b < 64) {
        int i = b * 256 + threadIdx.x;  // i = n*256 + k, n<64, k<256
        int n = i >> 8, k = i & 255;
        float s = 0.f;
        for (int j = 0; j < 128; ++j)
            s += W1[(size_t)k * 128 + j] * W2[(size_t)j * 64 + n];
        W12T[i] = (unsigned short)f32_to_bf16(s);
    } else {
        int d = threadIdx.x;
        if (d < 64) {
            float s = 0.f;
            for (int k = 0; k < 128; ++k) s += b1[k] * W2[(size_t)k * 64 + d];
            cvec[d] = s;
        }
        if (threadIdx.x == 64 && scalar_slot) *scalar_slot = 10.0f;
    }
}

// ================================================ K1: fused {hist+rank || MFMA GEMM}
// hist blocks: atomic-with-return on LINE-PADDED counters (cnt16[dst*16]) —
//   800K RMWs spread over 50000 lines instead of 782 (16x less line contention).
// gemm blocks: z[NN,64] bf16 = features @ W12 — MFMA pipe work that backfills
//   the CUs while hist waves sit in atomic-return latency (VALUBusy 0.4%).
__global__ __launch_bounds__(256) void fused_hist_gemm_kernel(
    const int* __restrict__ dst, int* __restrict__ cnt16, int* __restrict__ rank,
    const float* __restrict__ A, const unsigned short* __restrict__ BT,
    unsigned short* __restrict__ C) {
    __shared__ unsigned short As[64][40];
    __shared__ unsigned short Bs[64][40];

    if (blockIdx.x < CNT_NB) {
        int i = (blockIdx.x * 256 + threadIdx.x) * 8;
        if (i < NE) {  // NE % 8 == 0
            int4 d0 = *(const int4*)(dst + i);
            int4 d1 = *(const int4*)(dst + i + 4);
            int4 r0, r1;
            r0.x = atomicAdd(&cnt16[(size_t)d0.x * CPAD], 1);
            r0.y = atomicAdd(&cnt16[(size_t)d0.y * CPAD], 1);
            r0.z = atomicAdd(&cnt16[(size_t)d0.z * CPAD], 1);
            r0.w = atomicAdd(&cnt16[(size_t)d0.w * CPAD], 1);
            r1.x = atomicAdd(&cnt16[(size_t)d1.x * CPAD], 1);
            r1.y = atomicAdd(&cnt16[(size_t)d1.y * CPAD], 1);
            r1.z = atomicAdd(&cnt16[(size_t)d1.z * CPAD], 1);
            r1.w = atomicAdd(&cnt16[(size_t)d1.w * CPAD], 1);
            *(int4*)(rank + i) = r0;
            *(int4*)(rank + i + 4) = r1;
        }
        return;
    }

    constexpr int N = 64, K = 256;
    constexpr int NT = N / 16;
    constexpr int KS = K / 32;
    const int tid = threadIdx.x;
    const int wave = tid >> 6;
    const int lane = tid & 63;
    const int lm = lane & 15;
    const int lq = lane >> 4;
    const int row0 = (blockIdx.x - CNT_NB) * 64;
    const int m0 = wave * 16;

    f32x4 acc[NT] = {};

    for (int ks = 0; ks < KS; ++ks) {
        const int k0 = ks * 32;
        {
            int m = tid >> 2, kc = (tid & 3) * 8;
            int gm = row0 + m;
            if (gm >= NN) gm = NN - 1;
            float4 v0 = *(const float4*)(A + (size_t)gm * K + k0 + kc);
            float4 v1 = *(const float4*)(A + (size_t)gm * K + k0 + kc + 4);
            float f[8] = {v0.x, v0.y, v0.z, v0.w, v1.x, v1.y, v1.z, v1.w};
            *(u32x4*)&As[m][kc] = f32x8_to_bf16(f);
        }
        #pragma unroll
        for (int c = tid; c < N * 4; c += 256) {
            int n = c >> 2, kc = (c & 3) * 8;
            *(uint4*)&Bs[n][kc] = *(const uint4*)(BT + (size_t)n * K + k0 + kc);
        }
        __syncthreads();
        bf16x8 a = *(const bf16x8*)&As[m0 + lm][lq * 8];
        #pragma unroll
        for (int t = 0; t < NT; ++t) {
            bf16x8 b = *(const bf16x8*)&Bs[t * 16 + lm][lq * 8];
            acc[t] = __builtin_amdgcn_mfma_f32_16x16x32_bf16(a, b, acc[t], 0, 0, 0);
        }
        __syncthreads();
    }
    #pragma unroll
    for (int r = 0; r < 4; ++r) {
        int gm = row0 + m0 + lq * 4 + r;
        if (gm < NN) {
            #pragma unroll
            for (int t = 0; t < NT; ++t)
                C[(size_t)gm * N + t * 16 + lm] =
                    (unsigned short)f32_to_bf16(acc[t][r]);
        }
    }
}

// ------------------------------------------------ block scan (reads padded counters)
__global__ __launch_bounds__(256) void scan_block_kernel(const int* __restrict__ cnt16,
                                                         int* __restrict__ row_ptr,
                                                         int* __restrict__ partial) {
    __shared__ int wsums[4];
    int i = blockIdx.x * 256 + threadIdx.x;
    int v = (i < NN) ? cnt16[(size_t)i * CPAD] : 0;
    const int lane = threadIdx.x & 63;
    const int wid = threadIdx.x >> 6;
    int incl = v;
    #pragma unroll
    for (int off = 1; off < 64; off <<= 1) {
        int t = __shfl_up(incl, off);
        if (lane >= off) incl += t;
    }
    if (lane == 63) wsums[wid] = incl;
    __syncthreads();
    int woff = 0;
    #pragma unroll
    for (int w = 0; w < 4; ++w)
        if (w < wid) woff += wsums[w];
    if (i < NN) row_ptr[i] = woff + incl - v;
    if (threadIdx.x == 0)
        partial[blockIdx.x] = wsums[0] + wsums[1] + wsums[2] + wsums[3];
}

// ------------------------------------------------ scan of per-block partials
__global__ __launch_bounds__(256) void scan_partials_kernel(int* __restrict__ partial,
                                                            int* __restrict__ pexcl,
                                                            int* __restrict__ row_ptr,
                                                            int np) {
    __shared__ int wsums[4];
    int v = (threadIdx.x < np) ? partial[threadIdx.x] : 0;
    const int lane = threadIdx.x & 63;
    const int wid = threadIdx.x >> 6;
    int incl = v;
    #pragma unroll
    for (int off = 1; off < 64; off <<= 1) {
        int t = __shfl_up(incl, off);
        if (lane >= off) incl += t;
    }
    if (lane == 63) wsums[wid] = incl;
    __syncthreads();
    int woff = 0;
    #pragma unroll
    for (int w = 0; w < 4; ++w)
        if (w < wid) woff += wsums[w];
    if (threadIdx.x < np) pexcl[threadIdx.x] = woff + incl - v;
    if (threadIdx.x == 0) row_ptr[NN] = NE;
}

__global__ __launch_bounds__(256) void scan_add_kernel(int* __restrict__ row_ptr,
                                                       const int* __restrict__ pexcl,
                                                       int n) {
    int i = blockIdx.x * 256 + threadIdx.x;
    if (i < n) row_ptr[i] += pexcl[blockIdx.x];
}

// ------------------------------------------------ CSR fill (atomic-free, 4B rec)
__global__ __launch_bounds__(256) void fill_kernel(const int* __restrict__ src,
                                                   const int* __restrict__ dst,
                                                   const float* __restrict__ w,
                                                   const int* __restrict__ row_ptr,
                                                   const int* __restrict__ rank,
                                                   unsigned* __restrict__ er) {
    int i = (blockIdx.x * 256 + threadIdx.x) * 4;
    if (i < NE) {  // NE % 4 == 0
        int4 d = *(const int4*)(dst + i);
        int4 s = *(const int4*)(src + i);
        int4 rk = *(const int4*)(rank + i);
        float4 wv = *(const float4*)(w + i);
        er[row_ptr[d.x] + rk.x] = (f32_to_bf16(wv.x) << 16) | (unsigned)s.x;
        er[row_ptr[d.y] + rk.y] = (f32_to_bf16(wv.y) << 16) | (unsigned)s.y;
        er[row_ptr[d.z] + rk.z] = (f32_to_bf16(wv.z) << 16) | (unsigned)s.z;
        er[row_ptr[d.w] + rk.w] = (f32_to_bf16(wv.w) << 16) | (unsigned)s.w;
    }
}

// ------------------------------------------------ propagation D=64 (bf16, 4B rec)
// rec = bf16(w)<<16 | src (src < 65536 since NN=50000).  (known-best form, untouched)
// MODE 0: out = acc                         (conv1-fused; DEGW: also sum w)
// MODE 2: out = acc + degw[n]*c[d] + b2[d]  (conv2 epilogue)
// MODE 1: out = 0.9*acc + 0.1*h[n][d]       (APPNP step)
template <int MODE, bool OUT_BF16, bool DEGW>
__global__ __launch_bounds__(256, 4) void prop_kernel(
    const int* __restrict__ row_ptr, const unsigned* __restrict__ er,
    const unsigned short* __restrict__ x, const float* __restrict__ cvec,
    const float* __restrict__ b2, float* __restrict__ degw,
    const unsigned short* __restrict__ hbf, void* __restrict__ outv) {
    constexpr int D = 64;
    const int local = threadIdx.x >> 3;     // node within block (32/block)
    const int lane = threadIdx.x & 7;       // 8 threads/node, 16B each
    const int wbase = threadIdx.x & 56;     // group base lane within wave
    const int n = blockIdx.x * 32 + local;
    if (n >= NN) return;

    int e = row_ptr[n];
    const int end = row_ptr[n + 1];

    float acc[8] = {};
    float sw = 0.f;
    float f[8];

    for (; e + 7 < end; e += 8) {
        unsigned rq = er[e + lane];
        unsigned rr[8];
        #pragma unroll
        for (int q = 0; q < 8; ++q) rr[q] = __shfl(rq, wbase + q, 64);
        u32x4 uu[8];
        #pragma unroll
        for (int q = 0; q < 8; ++q)
            uu[q] = *(const u32x4*)(x + (size_t)(rr[q] & 0xffffu) * D + lane * 8);
        #pragma unroll
        for (int q = 0; q < 8; ++q) {
            float wq = __uint_as_float(rr[q] & 0xffff0000u);
            if (DEGW) sw += wq;
            bf16x8_to_f32(uu[q], f);
            #pragma unroll
            for (int j = 0; j < 8; ++j) acc[j] += wq * f[j];
        }
    }
    for (; e + 3 < end; e += 4) {
        unsigned rr[4];
        #pragma unroll
        for (int q = 0; q < 4; ++q) rr[q] = er[e + q];
        u32x4 uu[4];
        #pragma unroll
        for (int q = 0; q < 4; ++q)
            uu[q] = *(const u32x4*)(x + (size_t)(rr[q] & 0xffffu) * D + lane * 8);
        #pragma unroll
        for (int q = 0; q < 4; ++q) {
            float wq = __uint_as_float(rr[q] & 0xffff0000u);
            if (DEGW) sw += wq;
            bf16x8_to_f32(uu[q], f);
            #pragma unroll
            for (int j = 0; j < 8; ++j) acc[j] += wq * f[j];
        }
    }
    for (; e < end; ++e) {
        unsigned r0 = er[e];
        u32x4 u0 = *(const u32x4*)(x + (size_t)(r0 & 0xffffu) * D + lane * 8);
        float w0 = __uint_as_float(r0 & 0xffff0000u);
        if (DEGW) sw += w0;
        bf16x8_to_f32(u0, f);
        #pragma unroll
        for (int j = 0; j < 8; ++j) acc[j] += w0 * f[j];
    }

    if (DEGW) {
        if (lane == 0) degw[n] = sw;
    }

    float r[8];
    if (MODE == 0) {
        #pragma unroll
        for (int j = 0; j < 8; ++j) r[j] = acc[j];
    } else if (MODE == 2) {
        float dw = degw[n];
        #pragma unroll
        for (int j = 0; j < 8; ++j)
            r[j] = acc[j] + dw * cvec[lane * 8 + j] + b2[lane * 8 + j];
    } else {
        u32x4 uh = *(const u32x4*)(hbf + (size_t)n * D + lane * 8);
        float fh[8];
        bf16x8_to_f32(uh, fh);
        #pragma unroll
        for (int j = 0; j < 8; ++j) r[j] = 0.9f * acc[j] + 0.1f * fh[j];
    }

    if (OUT_BF16) {
        *(u32x4*)((unsigned short*)outv + (size_t)n * D + lane * 8) =
            f32x8_to_bf16(r);
    } else {
        float* o = (float*)outv + (size_t)n * D + lane * 8;
        *(float4*)(o + 0) = make_float4(r[0], r[1], r[2], r[3]);
        *(float4*)(o + 4) = make_float4(r[4], r[5], r[6], r[7]);
    }
}

// ------------------------------------------------ launch
extern "C" void kernel_launch(void* const* d_in, const int* in_sizes, int n_in,
                              void* d_out, int out_size, void* d_ws, size_t ws_size,
                              hipStream_t stream) {
    const float* features = (const float*)d_in[0];
    const int* edge_index = (const int*)d_in[1];
    const float* edge_w = (const float*)d_in[2];
    const float* W1 = (const float*)d_in[3];
    const float* b1 = (const float*)d_in[4];
    const float* W2 = (const float*)d_in[5];
    const float* b2 = (const float*)d_in[6];
    const int* src = edge_index;        // edge_index[0]
    const int* dst = edge_index + NE;   // edge_index[1]

    char* ws = (char*)d_ws;
    auto carve = [&](size_t bytes) {
        char* p = ws;
        ws += (bytes + 255) & ~(size_t)255;
        return p;
    };
    int* cnt16 = (int*)carve((size_t)NN * CPAD * 4);   // line-padded counters
    int* rank = (int*)carve((size_t)NE * 4);
    int* row_ptr = (int*)carve((size_t)(NN + 1) * 4);
    int* partial = (int*)carve((size_t)SCAN_NB * 4);
    int* pexcl = (int*)carve((size_t)SCAN_NB * 4);
    unsigned* erec = (unsigned*)carve((size_t)NE * 4);
    float* degw = (float*)carve((size_t)NN * 4);
    float* cvec = (float*)carve((size_t)64 * 4);
    unsigned short* W12T = (unsigned short*)carve((size_t)64 * 256 * 2);
    unsigned short* z_bf = (unsigned short*)carve((size_t)NN * 64 * 2);
    unsigned short* p1_bf = (unsigned short*)carve((size_t)NN * 64 * 2);
    unsigned short* h_bf = (unsigned short*)carve((size_t)NN * 64 * 2);
    unsigned short* xb0 = (unsigned short*)carve((size_t)NN * 64 * 2);
    unsigned short* xb1 = (unsigned short*)carve((size_t)NN * 64 * 2);

    const int EB4 = (NE / 4 + 255) / 256;
    const int PB = (NN + 31) / 32;   // prop blocks (32 nodes each)

    float* scalar_slot =
        (out_size > NN * 64) ? ((float*)d_out + (size_t)NN * 64) : nullptr;

    // ---- K0: {W12T, cvec, out scalar} (tiny; unblocks GEMM in K1) ----
    hipMemsetAsync(cnt16, 0, (size_t)NN * CPAD * 4, stream);
    prep_kernel<<<65, 256, 0, stream>>>(W1, W2, W12T, b1, cvec, scalar_slot);

    // ---- K1: {hist+rank (line-padded atomics) || GEMM} in one grid ----
    fused_hist_gemm_kernel<<<CNT_NB + GEMM_NB, 256, 0, stream>>>(
        dst, cnt16, rank, features, W12T, z_bf);

    // ---- scan ----
    scan_block_kernel<<<SCAN_NB, 256, 0, stream>>>(cnt16, row_ptr, partial);
    scan_partials_kernel<<<1, 256, 0, stream>>>(partial, pexcl, row_ptr, SCAN_NB);
    scan_add_kernel<<<SCAN_NB, 256, 0, stream>>>(row_ptr, pexcl, NN);

    // ---- CSR fill (atomic-free) ----
    fill_kernel<<<EB4, 256, 0, stream>>>(src, dst, edge_w, row_ptr, rank, erec);

    // ---- p1 = prop(z) [+degw];  h = prop(p1) + degw*c + b2 ----
    prop_kernel<0, true, true><<<PB, 256, 0, stream>>>(row_ptr, erec, z_bf, nullptr,
                                                       nullptr, degw, nullptr,
                                                       p1_bf);
    prop_kernel<2, true, false><<<PB, 256, 0, stream>>>(row_ptr, erec, p1_bf, cvec,
                                                        b2, degw, nullptr, h_bf);

    // ---- APPNP: 10 steps of x = 0.9*prop(x) + 0.1*h ----
    const unsigned short* x_cur = h_bf;
    for (int k = 0; k < 9; ++k) {
        unsigned short* out = (k & 1) ? xb1 : xb0;
        prop_kernel<1, true, false><<<PB, 256, 0, stream>>>(row_ptr, erec, x_cur,
                                                            nullptr, nullptr,
                                                            nullptr, h_bf, out);
        x_cur = out;
    }
    prop_kernel<1, false, false><<<PB, 256, 0, stream>>>(row_ptr, erec, x_cur,
                                                         nullptr, nullptr, nullptr,
                                                         h_bf, (float*)d_out);
}

// Round 8
// 328.816 us; speedup vs baseline: 1.5701x; 1.0510x over previous
//
#include <hip/hip_runtime.h>

#define NN 50000
#define NE 800000
#define EPB 2048                       // edges per P1 block
#define NB1 ((NE + EPB - 1) / EPB)     // 391
#define NB1P 512                       // padded column count (power of 2)
#define NBUK ((NN + 255) / 256)        // 196 coarse buckets (dst>>8)
#define GEMM_NB ((NN + 63) / 64)       // 782

typedef short bf16x8 __attribute__((ext_vector_type(8)));
typedef float f32x4 __attribute__((ext_vector_type(4)));
typedef unsigned u32x4 __attribute__((ext_vector_type(4)));

// ------------------------------------------------ bf16 helpers (ushort = bf16)
__device__ inline void bf16x8_to_f32(const u32x4 v, float* f) {
    f[0] = __uint_as_float(v.x << 16);
    f[1] = __uint_as_float(v.x & 0xffff0000u);
    f[2] = __uint_as_float(v.y << 16);
    f[3] = __uint_as_float(v.y & 0xffff0000u);
    f[4] = __uint_as_float(v.z << 16);
    f[5] = __uint_as_float(v.z & 0xffff0000u);
    f[6] = __uint_as_float(v.w << 16);
    f[7] = __uint_as_float(v.w & 0xffff0000u);
}

__device__ inline unsigned f32_to_bf16(float x) {  // RTNE
    unsigned u = __float_as_uint(x);
    return (u + 0x7fffu + ((u >> 16) & 1u)) >> 16;
}

__device__ inline u32x4 f32x8_to_bf16(const float* f) {
    u32x4 v;
    v.x = f32_to_bf16(f[0]) | (f32_to_bf16(f[1]) << 16);
    v.y = f32_to_bf16(f[2]) | (f32_to_bf16(f[3]) << 16);
    v.z = f32_to_bf16(f[4]) | (f32_to_bf16(f[5]) << 16);
    v.w = f32_to_bf16(f[6]) | (f32_to_bf16(f[7]) << 16);
    return v;
}

// ================================================ kA: {P1-count, W12T, cvec, scalar}
// P1-count: per-block LDS histogram over 196 coarse buckets -> H[bin][blk].
// No global atomics anywhere.
__global__ __launch_bounds__(256) void kA_kernel(
    const int* __restrict__ dst, int* __restrict__ H,
    const float* __restrict__ W1, const float* __restrict__ W2,
    unsigned short* __restrict__ W12T, const float* __restrict__ b1,
    float* __restrict__ cvec, float* __restrict__ scalar_slot) {
    const int b = blockIdx.x;
    if (b < NB1) {
        __shared__ int lh[NBUK];
        for (int t = threadIdx.x; t < NBUK; t += 256) lh[t] = 0;
        __syncthreads();
        int i = b * EPB + threadIdx.x * 8;
        if (i < NE) {  // NE % 8 == 0, chunks 8-aligned
            int4 d0 = *(const int4*)(dst + i);
            int4 d1 = *(const int4*)(dst + i + 4);
            atomicAdd(&lh[d0.x >> 8], 1);
            atomicAdd(&lh[d0.y >> 8], 1);
            atomicAdd(&lh[d0.z >> 8], 1);
            atomicAdd(&lh[d0.w >> 8], 1);
            atomicAdd(&lh[d1.x >> 8], 1);
            atomicAdd(&lh[d1.y >> 8], 1);
            atomicAdd(&lh[d1.z >> 8], 1);
            atomicAdd(&lh[d1.w >> 8], 1);
        }
        __syncthreads();
        for (int t = threadIdx.x; t < NBUK; t += 256) H[t * NB1P + b] = lh[t];
    } else if (b < NB1 + 64) {
        int i = (b - NB1) * 256 + threadIdx.x;  // i = n*256 + k, n<64, k<256
        int n = i >> 8, k = i & 255;
        float s = 0.f;
        for (int j = 0; j < 128; ++j)
            s += W1[(size_t)k * 128 + j] * W2[(size_t)j * 64 + n];
        W12T[i] = (unsigned short)f32_to_bf16(s);
    } else {
        int d = threadIdx.x;
        if (d < 64) {
            float s = 0.f;
            for (int k = 0; k < 128; ++k) s += b1[k] * W2[(size_t)k * 64 + d];
            cvec[d] = s;
        }
        if (threadIdx.x == 64 && scalar_slot) *scalar_slot = 10.0f;
    }
}

// ================================================ kC1: exclusive scan of each H row
// (one block per bucket; 512 padded columns, 2 contiguous elems/thread; in-place)
__global__ __launch_bounds__(256) void kC1_kernel(int* __restrict__ H,
                                                  int* __restrict__ colsum) {
    __shared__ int ws[4];
    int* row = H + (size_t)blockIdx.x * NB1P;
    const int t = threadIdx.x;
    int a0 = row[2 * t], a1 = row[2 * t + 1];
    int p = a0 + a1;
    const int lane = t & 63;
    const int wid = t >> 6;
    int incl = p;
    #pragma unroll
    for (int off = 1; off < 64; off <<= 1) {
        int q = __shfl_up(incl, off);
        if (lane >= off) incl += q;
    }
    if (lane == 63) ws[wid] = incl;
    __syncthreads();
    int woff = 0;
    #pragma unroll
    for (int w = 0; w < 4; ++w)
        if (w < wid) woff += ws[w];
    int ex = woff + incl - p;
    row[2 * t] = ex;
    row[2 * t + 1] = ex + a0;
    if (t == 0) colsum[blockIdx.x] = ws[0] + ws[1] + ws[2] + ws[3];
}

// ================================================ kC2: scan bucket totals -> base
__global__ __launch_bounds__(256) void kC2_kernel(const int* __restrict__ colsum,
                                                  int* __restrict__ base,
                                                  int* __restrict__ row_ptr) {
    __shared__ int ws[4];
    const int t = threadIdx.x;
    int v = (t < NBUK) ? colsum[t] : 0;
    const int lane = t & 63;
    const int wid = t >> 6;
    int incl = v;
    #pragma unroll
    for (int off = 1; off < 64; off <<= 1) {
        int q = __shfl_up(incl, off);
        if (lane >= off) incl += q;
    }
    if (lane == 63) ws[wid] = incl;
    __syncthreads();
    int woff = 0;
    #pragma unroll
    for (int w = 0; w < 4; ++w)
        if (w < wid) woff += ws[w];
    if (t < NBUK) base[t] = woff + incl - v;
    if (t == 0) {
        base[NBUK] = NE;
        row_ptr[NN] = NE;
    }
}

// ================================================ kD: {P1-scatter || MFMA GEMM}
// P1-scatter: rank within (block,bin) via LDS atomic-return (cheap), write
// records into bucket-grouped er1/d8. GEMM backfills CUs.
__global__ __launch_bounds__(256) void kD_kernel(
    const int* __restrict__ src, const int* __restrict__ dst,
    const float* __restrict__ w, const int* __restrict__ H,
    const int* __restrict__ base, unsigned* __restrict__ er1,
    unsigned char* __restrict__ d8, const float* __restrict__ A,
    const unsigned short* __restrict__ BT, unsigned short* __restrict__ C) {
    __shared__ unsigned short As[64][40];
    __shared__ unsigned short Bs[64][40];
    __shared__ int lh[NBUK];
    __shared__ int lb[NBUK];
    const int b = blockIdx.x;

    if (b < NB1) {
        for (int t = threadIdx.x; t < NBUK; t += 256) {
            lh[t] = 0;
            lb[t] = base[t] + H[(size_t)t * NB1P + b];  // this block's range per bin
        }
        __syncthreads();
        int i = b * EPB + threadIdx.x * 8;
        if (i < NE) {
            int4 d0 = *(const int4*)(dst + i);
            int4 d1 = *(const int4*)(dst + i + 4);
            int4 s0 = *(const int4*)(src + i);
            int4 s1 = *(const int4*)(src + i + 4);
            float4 w0 = *(const float4*)(w + i);
            float4 w1 = *(const float4*)(w + i + 4);
            int dd[8] = {d0.x, d0.y, d0.z, d0.w, d1.x, d1.y, d1.z, d1.w};
            int ss[8] = {s0.x, s0.y, s0.z, s0.w, s1.x, s1.y, s1.z, s1.w};
            float ww[8] = {w0.x, w0.y, w0.z, w0.w, w1.x, w1.y, w1.z, w1.w};
            #pragma unroll
            for (int q = 0; q < 8; ++q) {
                int bin = dd[q] >> 8;
                int lr = atomicAdd(&lh[bin], 1);  // LDS return: fast
                int pos = lb[bin] + lr;
                er1[pos] = (f32_to_bf16(ww[q]) << 16) | (unsigned)ss[q];
                d8[pos] = (unsigned char)(dd[q] & 255);
            }
        }
        return;
    }

    constexpr int N = 64, K = 256;
    constexpr int NT = N / 16;
    constexpr int KS = K / 32;
    const int tid = threadIdx.x;
    const int wave = tid >> 6;
    const int lane = tid & 63;
    const int lm = lane & 15;
    const int lq = lane >> 4;
    const int row0 = (b - NB1) * 64;
    const int m0 = wave * 16;

    f32x4 acc[NT] = {};

    for (int ks = 0; ks < KS; ++ks) {
        const int k0 = ks * 32;
        {
            int m = tid >> 2, kc = (tid & 3) * 8;
            int gm = row0 + m;
            if (gm >= NN) gm = NN - 1;
            float4 v0 = *(const float4*)(A + (size_t)gm * K + k0 + kc);
            float4 v1 = *(const float4*)(A + (size_t)gm * K + k0 + kc + 4);
            float f[8] = {v0.x, v0.y, v0.z, v0.w, v1.x, v1.y, v1.z, v1.w};
            *(u32x4*)&As[m][kc] = f32x8_to_bf16(f);
        }
        #pragma unroll
        for (int c = tid; c < N * 4; c += 256) {
            int n = c >> 2, kc = (c & 3) * 8;
            *(uint4*)&Bs[n][kc] = *(const uint4*)(BT + (size_t)n * K + k0 + kc);
        }
        __syncthreads();
        bf16x8 a = *(const bf16x8*)&As[m0 + lm][lq * 8];
        #pragma unroll
        for (int t = 0; t < NT; ++t) {
            bf16x8 bb = *(const bf16x8*)&Bs[t * 16 + lm][lq * 8];
            acc[t] = __builtin_amdgcn_mfma_f32_16x16x32_bf16(a, bb, acc[t], 0, 0, 0);
        }
        __syncthreads();
    }
    #pragma unroll
    for (int r = 0; r < 4; ++r) {
        int gm = row0 + m0 + lq * 4 + r;
        if (gm < NN) {
            #pragma unroll
            for (int t = 0; t < NT; ++t)
                C[(size_t)gm * N + t * 16 + lm] =
                    (unsigned short)f32_to_bf16(acc[t][r]);
        }
    }
}

// ================================================ kE: per-bucket final CSR build
// One block per bucket (256 nodes, ~4096 edges): LDS count -> scan -> row_ptr,
// then LDS-cursor placement into er. No global atomics.
__global__ __launch_bounds__(256) void kE_kernel(
    const int* __restrict__ base, const unsigned char* __restrict__ d8,
    const unsigned* __restrict__ er1, int* __restrict__ row_ptr,
    unsigned* __restrict__ er) {
    __shared__ int cnt[256];
    __shared__ int cur[256];
    __shared__ int ws[4];
    const int k = blockIdx.x;
    const int t = threadIdx.x;
    const int s = base[k];
    const int e_end = base[k + 1];

    cnt[t] = 0;
    __syncthreads();
    for (int e = s + t; e < e_end; e += 256) atomicAdd(&cnt[d8[e]], 1);
    __syncthreads();

    int v = cnt[t];
    const int lane = t & 63;
    const int wid = t >> 6;
    int incl = v;
    #pragma unroll
    for (int off = 1; off < 64; off <<= 1) {
        int q = __shfl_up(incl, off);
        if (lane >= off) incl += q;
    }
    if (lane == 63) ws[wid] = incl;
    __syncthreads();
    int woff = 0;
    #pragma unroll
    for (int w = 0; w < 4; ++w)
        if (w < wid) woff += ws[w];
    int ex = woff + incl - v;

    int node = k * 256 + t;
    if (node < NN) row_ptr[node] = s + ex;
    cur[t] = s + ex;
    __syncthreads();

    for (int e = s + t; e < e_end; e += 256) {
        int p = atomicAdd(&cur[d8[e]], 1);
        er[p] = er1[e];
    }
}

// ------------------------------------------------ propagation D=64 (bf16, 4B rec)
// rec = bf16(w)<<16 | src (src < 65536 since NN=50000).  (known-best form)
// MODE 0: out = acc                         (conv1-fused; DEGW: also sum w)
// MODE 2: out = acc + degw[n]*c[d] + b2[d]  (conv2 epilogue)
// MODE 1: out = 0.9*acc + 0.1*h[n][d]       (APPNP step)
template <int MODE, bool OUT_BF16, bool DEGW>
__global__ __launch_bounds__(256, 4) void prop_kernel(
    const int* __restrict__ row_ptr, const unsigned* __restrict__ er,
    const unsigned short* __restrict__ x, const float* __restrict__ cvec,
    const float* __restrict__ b2, float* __restrict__ degw,
    const unsigned short* __restrict__ hbf, void* __restrict__ outv) {
    constexpr int D = 64;
    const int local = threadIdx.x >> 3;     // node within block (32/block)
    const int lane = threadIdx.x & 7;       // 8 threads/node, 16B each
    const int wbase = threadIdx.x & 56;     // group base lane within wave
    const int n = blockIdx.x * 32 + local;
    if (n >= NN) return;

    int e = row_ptr[n];
    const int end = row_ptr[n + 1];

    float acc[8] = {};
    float sw = 0.f;
    float f[8];

    for (; e + 7 < end; e += 8) {
        unsigned rq = er[e + lane];
        unsigned rr[8];
        #pragma unroll
        for (int q = 0; q < 8; ++q) rr[q] = __shfl(rq, wbase + q, 64);
        u32x4 uu[8];
        #pragma unroll
        for (int q = 0; q < 8; ++q)
            uu[q] = *(const u32x4*)(x + (size_t)(rr[q] & 0xffffu) * D + lane * 8);
        #pragma unroll
        for (int q = 0; q < 8; ++q) {
            float wq = __uint_as_float(rr[q] & 0xffff0000u);
            if (DEGW) sw += wq;
            bf16x8_to_f32(uu[q], f);
            #pragma unroll
            for (int j = 0; j < 8; ++j) acc[j] += wq * f[j];
        }
    }
    for (; e + 3 < end; e += 4) {
        unsigned rr[4];
        #pragma unroll
        for (int q = 0; q < 4; ++q) rr[q] = er[e + q];
        u32x4 uu[4];
        #pragma unroll
        for (int q = 0; q < 4; ++q)
            uu[q] = *(const u32x4*)(x + (size_t)(rr[q] & 0xffffu) * D + lane * 8);
        #pragma unroll
        for (int q = 0; q < 4; ++q) {
            float wq = __uint_as_float(rr[q] & 0xffff0000u);
            if (DEGW) sw += wq;
            bf16x8_to_f32(uu[q], f);
            #pragma unroll
            for (int j = 0; j < 8; ++j) acc[j] += wq * f[j];
        }
    }
    for (; e < end; ++e) {
        unsigned r0 = er[e];
        u32x4 u0 = *(const u32x4*)(x + (size_t)(r0 & 0xffffu) * D + lane * 8);
        float w0 = __uint_as_float(r0 & 0xffff0000u);
        if (DEGW) sw += w0;
        bf16x8_to_f32(u0, f);
        #pragma unroll
        for (int j = 0; j < 8; ++j) acc[j] += w0 * f[j];
    }

    if (DEGW) {
        if (lane == 0) degw[n] = sw;
    }

    float r[8];
    if (MODE == 0) {
        #pragma unroll
        for (int j = 0; j < 8; ++j) r[j] = acc[j];
    } else if (MODE == 2) {
        float dw = degw[n];
        #pragma unroll
        for (int j = 0; j < 8; ++j)
            r[j] = acc[j] + dw * cvec[lane * 8 + j] + b2[lane * 8 + j];
    } else {
        u32x4 uh = *(const u32x4*)(hbf + (size_t)n * D + lane * 8);
        float fh[8];
        bf16x8_to_f32(uh, fh);
        #pragma unroll
        for (int j = 0; j < 8; ++j) r[j] = 0.9f * acc[j] + 0.1f * fh[j];
    }

    if (OUT_BF16) {
        *(u32x4*)((unsigned short*)outv + (size_t)n * D + lane * 8) =
            f32x8_to_bf16(r);
    } else {
        float* o = (float*)outv + (size_t)n * D + lane * 8;
        *(float4*)(o + 0) = make_float4(r[0], r[1], r[2], r[3]);
        *(float4*)(o + 4) = make_float4(r[4], r[5], r[6], r[7]);
    }
}

// ------------------------------------------------ launch
extern "C" void kernel_launch(void* const* d_in, const int* in_sizes, int n_in,
                              void* d_out, int out_size, void* d_ws, size_t ws_size,
                              hipStream_t stream) {
    const float* features = (const float*)d_in[0];
    const int* edge_index = (const int*)d_in[1];
    const float* edge_w = (const float*)d_in[2];
    const float* W1 = (const float*)d_in[3];
    const float* b1 = (const float*)d_in[4];
    const float* W2 = (const float*)d_in[5];
    const float* b2 = (const float*)d_in[6];
    const int* src = edge_index;        // edge_index[0]
    const int* dst = edge_index + NE;   // edge_index[1]

    char* ws = (char*)d_ws;
    auto carve = [&](size_t bytes) {
        char* p = ws;
        ws += (bytes + 255) & ~(size_t)255;
        return p;
    };
    int* H = (int*)carve((size_t)NBUK * NB1P * 4);    // per-(bin,block) matrix
    int* colsum = (int*)carve((size_t)NBUK * 4);
    int* base = (int*)carve((size_t)(NBUK + 1) * 4);
    int* row_ptr = (int*)carve((size_t)(NN + 1) * 4);
    unsigned* er1 = (unsigned*)carve((size_t)NE * 4); // bucket-grouped records
    unsigned char* d8 = (unsigned char*)carve((size_t)NE);
    unsigned* erec = (unsigned*)carve((size_t)NE * 4);
    float* degw = (float*)carve((size_t)NN * 4);
    float* cvec = (float*)carve((size_t)64 * 4);
    unsigned short* W12T = (unsigned short*)carve((size_t)64 * 256 * 2);
    unsigned short* z_bf = (unsigned short*)carve((size_t)NN * 64 * 2);
    unsigned short* p1_bf = (unsigned short*)carve((size_t)NN * 64 * 2);
    unsigned short* h_bf = (unsigned short*)carve((size_t)NN * 64 * 2);
    unsigned short* xb0 = (unsigned short*)carve((size_t)NN * 64 * 2);
    unsigned short* xb1 = (unsigned short*)carve((size_t)NN * 64 * 2);

    const int PB = (NN + 31) / 32;   // prop blocks (32 nodes each)

    float* scalar_slot =
        (out_size > NN * 64) ? ((float*)d_out + (size_t)NN * 64) : nullptr;

    // ---- kA: {P1-count, W12T, cvec, scalar} ----
    hipMemsetAsync(H, 0, (size_t)NBUK * NB1P * 4, stream);
    kA_kernel<<<NB1 + 64 + 1, 256, 0, stream>>>(dst, H, W1, W2, W12T, b1, cvec,
                                                scalar_slot);

    // ---- kC1/kC2: matrix scans (atomic-free placement ranges) ----
    kC1_kernel<<<NBUK, 256, 0, stream>>>(H, colsum);
    kC2_kernel<<<1, 256, 0, stream>>>(colsum, base, row_ptr);

    // ---- kD: {P1-scatter || GEMM z = F @ W12} ----
    kD_kernel<<<NB1 + GEMM_NB, 256, 0, stream>>>(src, dst, edge_w, H, base, er1,
                                                 d8, features, W12T, z_bf);

    // ---- kE: per-bucket final CSR (row_ptr + er) ----
    kE_kernel<<<NBUK, 256, 0, stream>>>(base, d8, er1, row_ptr, erec);

    // ---- p1 = prop(z) [+degw];  h = prop(p1) + degw*c + b2 ----
    prop_kernel<0, true, true><<<PB, 256, 0, stream>>>(row_ptr, erec, z_bf, nullptr,
                                                       nullptr, degw, nullptr,
                                                       p1_bf);
    prop_kernel<2, true, false><<<PB, 256, 0, stream>>>(row_ptr, erec, p1_bf, cvec,
                                                        b2, degw, nullptr, h_bf);

    // ---- APPNP: 10 steps of x = 0.9*prop(x) + 0.1*h ----
    const unsigned short* x_cur = h_bf;
    for (int k = 0; k < 9; ++k) {
        unsigned short* out = (k & 1) ? xb1 : xb0;
        prop_kernel<1, true, false><<<PB, 256, 0, stream>>>(row_ptr, erec, x_cur,
                                                            nullptr, nullptr,
                                                            nullptr, h_bf, out);
        x_cur = out;
    }
    prop_kernel<1, false, false><<<PB, 256, 0, stream>>>(row_ptr, erec, x_cur,
                                                         nullptr, nullptr, nullptr,
                                                         h_bf, (float*)d_out);
}